// Round 3
// baseline (2554.788 us; speedup 1.0000x reference)
//
#include <hip/hip_runtime.h>
#include <hip/hip_bf16.h>

#define B_  2
#define T_  2048
#define C_  1024
#define H_  16
#define HS_ 64
#define M_  (B_*T_)    // 4096
#define N_  (H_*HS_)   // 1024
#define K_  C_         // 1024

union U8 { uint4 v; unsigned short s[8]; };

__device__ __forceinline__ float bf2f(unsigned short u) {
    return __uint_as_float(((unsigned int)u) << 16);
}
__device__ __forceinline__ unsigned short f2bf(float f) {
    unsigned int u = __float_as_uint(f);
    return (unsigned short)((u + 0x7fffu + ((u >> 16) & 1u)) >> 16);
}

// ---------------------------------------------------------------------------
// Kernel 0: detect whether external tensors are fp32 or bf16 storage.
// Probes first 1024 ushorts of q_x (N(0,1) data):
//   true bf16 array      : no exact-zero ushorts, no exponent >= 134
//   fp32 full-precision  : ~48% of even (mantissa) halves have exponent >= 134
//   fp32 w/ bf16 values  : even halves are exactly 0
// flag = 1 -> fp32 storage, 0 -> bf16 storage.
// ---------------------------------------------------------------------------
__global__ void detect_kernel(const unsigned short* __restrict__ x,
                              int* __restrict__ flag) {
    __shared__ int bigexp, zeros;
    if (threadIdx.x == 0) { bigexp = 0; zeros = 0; }
    __syncthreads();
    int cbig = 0, czero = 0;
    for (int i = threadIdx.x; i < 1024; i += 256) {
        const unsigned short u = x[i];
        if (u == 0) czero++;
        else if (((u >> 7) & 0xFF) >= 134) cbig++;   // |bf16| >= 128
    }
    atomicAdd(&bigexp, cbig);
    atomicAdd(&zeros, czero);
    __syncthreads();
    if (threadIdx.x == 0) *flag = (bigexp > 100 || zeros > 100) ? 1 : 0;
}

// ---------------------------------------------------------------------------
// Kernel 1: QKV projection. out[p] = x @ W[p] + b[p] -> bf16 [B,H,T,HS]
// grid = (N/64, M/64, 3), block = 256. Dual-dtype loads via *flagp.
// ---------------------------------------------------------------------------
__global__ __launch_bounds__(256) void qkv_gemm(
    const void* __restrict__ x,
    const void* __restrict__ wq, const void* __restrict__ bq,
    const void* __restrict__ wk, const void* __restrict__ bk,
    const void* __restrict__ wv, const void* __restrict__ bv,
    unsigned short* __restrict__ qb, unsigned short* __restrict__ kb,
    unsigned short* __restrict__ vb, const int* __restrict__ flagp)
{
    const bool f32 = (*flagp != 0);
    const int p = blockIdx.z;
    const void* W    = (p == 0) ? wq : (p == 1) ? wk : wv;
    const void* bias = (p == 0) ? bq : (p == 1) ? bk : bv;
    unsigned short* out = (p == 0) ? qb : (p == 1) ? kb : vb;

    __shared__ float As[32][64];   // [k][m]
    __shared__ float Ws[32][64];   // [k][n]

    const int tid = threadIdx.x;
    const int tx = tid & 15, ty = tid >> 4;
    const int m0 = blockIdx.y * 64, n0 = blockIdx.x * 64;

    const int ar  = tid >> 2;          // 0..63  m-row in tile
    const int akc = (tid & 3) * 8;     // k offset (8 elems/thread)
    const int wkr = tid >> 3;          // 0..31  k-row
    const int wnc = (tid & 7) * 8;     // n offset

    float acc[4][4] = {};

    for (int k0 = 0; k0 < K_; k0 += 32) {
        float av8[8], wv8[8];
        const size_t aoff = (size_t)(m0 + ar) * K_ + k0 + akc;
        const size_t woff = (size_t)(k0 + wkr) * N_ + n0 + wnc;
        if (f32) {
            const float4* pa = (const float4*)((const float*)x + aoff);
            float4 a0 = pa[0], a1 = pa[1];
            av8[0]=a0.x; av8[1]=a0.y; av8[2]=a0.z; av8[3]=a0.w;
            av8[4]=a1.x; av8[5]=a1.y; av8[6]=a1.z; av8[7]=a1.w;
            const float4* pw = (const float4*)((const float*)W + woff);
            float4 w0 = pw[0], w1 = pw[1];
            wv8[0]=w0.x; wv8[1]=w0.y; wv8[2]=w0.z; wv8[3]=w0.w;
            wv8[4]=w1.x; wv8[5]=w1.y; wv8[6]=w1.z; wv8[7]=w1.w;
        } else {
            U8 a; a.v = *(const uint4*)((const unsigned short*)x + aoff);
            U8 w; w.v = *(const uint4*)((const unsigned short*)W + woff);
#pragma unroll
            for (int j = 0; j < 8; j++) { av8[j] = bf2f(a.s[j]); wv8[j] = bf2f(w.s[j]); }
        }
        __syncthreads();
#pragma unroll
        for (int j = 0; j < 8; j++) As[akc + j][ar] = av8[j];
#pragma unroll
        for (int j = 0; j < 8; j++) Ws[wkr][wnc + j] = wv8[j];
        __syncthreads();
#pragma unroll 8
        for (int kk = 0; kk < 32; kk++) {
            const float4 av  = *(const float4*)&As[kk][ty * 4];
            const float4 bv4 = *(const float4*)&Ws[kk][tx * 4];
            const float a4[4] = {av.x, av.y, av.z, av.w};
            const float b4[4] = {bv4.x, bv4.y, bv4.z, bv4.w};
#pragma unroll
            for (int i = 0; i < 4; i++)
#pragma unroll
                for (int j = 0; j < 4; j++) acc[i][j] += a4[i] * b4[j];
        }
    }

    const int n = n0 + tx * 4;          // n0 % 64 == 0 -> head-aligned
    const int h = n >> 6;
    const int d = n & 63;
    float bz[4];
#pragma unroll
    for (int j = 0; j < 4; j++)
        bz[j] = f32 ? ((const float*)bias)[n + j]
                    : bf2f(((const unsigned short*)bias)[n + j]);
#pragma unroll
    for (int i = 0; i < 4; i++) {
        const int m = m0 + ty * 4 + i;
        const int b = m / T_;
        const int t = m % T_;
        ushort4 st;
        st.x = f2bf(acc[i][0] + bz[0]);
        st.y = f2bf(acc[i][1] + bz[1]);
        st.z = f2bf(acc[i][2] + bz[2]);
        st.w = f2bf(acc[i][3] + bz[3]);
        *(ushort4*)(out + ((size_t)(b * H_ + h) * T_ + t) * HS_ + d) = st;
    }
}

// ---------------------------------------------------------------------------
// Kernel 2: RoPE in-place on bf16 q/k intermediates [B,H,T,HS].
// ---------------------------------------------------------------------------
__global__ __launch_bounds__(256) void rope_kernel(unsigned short* __restrict__ qb,
                                                   unsigned short* __restrict__ kb)
{
    const int idx = blockIdx.x * 256 + threadIdx.x;
    const int d  = idx & 31;
    const int t  = (idx >> 5) & (T_ - 1);
    const int bh = idx >> 16;            // T_*32 == 65536
    const size_t base = ((size_t)bh * T_ + t) * HS_;

    const float inv_freq = powf(10000.0f, -(float)d * (1.0f / 32.0f));
    float s, c;
    sincosf((float)t * inv_freq, &s, &c);

    {
        float x1 = bf2f(qb[base + d]), x2 = bf2f(qb[base + d + 32]);
        qb[base + d]      = f2bf(x1 * c - x2 * s);
        qb[base + d + 32] = f2bf(x2 * c + x1 * s);
    }
    {
        float x1 = bf2f(kb[base + d]), x2 = bf2f(kb[base + d + 32]);
        kb[base + d]      = f2bf(x1 * c - x2 * s);
        kb[base + d + 32] = f2bf(x2 * c + x1 * s);
    }
}

// ---------------------------------------------------------------------------
// Kernel 3: causal flash attention, fp32 math, bf16 internal I/O.
// grid = (B*H, T/128), block = 128: one q row/thread, 64-row K/V tiles in LDS.
// ---------------------------------------------------------------------------
__global__ __launch_bounds__(128) void attn_kernel(
    const unsigned short* __restrict__ qb, const unsigned short* __restrict__ kb,
    const unsigned short* __restrict__ vb, unsigned short* __restrict__ yb)
{
    __shared__ float4 Ks[64 * 16];
    __shared__ float4 Vs[64 * 16];

    const int bh = blockIdx.x;             // b*H + h
    const int b = bh >> 4, h = bh & 15;
    const int r0 = blockIdx.y * 128;
    const int tid = threadIdx.x;
    const int tq = r0 + tid;

    const unsigned short* qrow = qb + ((size_t)bh * T_ + tq) * HS_;
    float4 qf[16];
#pragma unroll
    for (int j = 0; j < 8; j++) {
        U8 u; u.v = *(const uint4*)(qrow + 8 * j);
        qf[2*j]   = make_float4(bf2f(u.s[0])*0.125f, bf2f(u.s[1])*0.125f,
                                bf2f(u.s[2])*0.125f, bf2f(u.s[3])*0.125f);
        qf[2*j+1] = make_float4(bf2f(u.s[4])*0.125f, bf2f(u.s[5])*0.125f,
                                bf2f(u.s[6])*0.125f, bf2f(u.s[7])*0.125f);
    }
    float4 of[16];
#pragma unroll
    for (int i = 0; i < 16; i++) of[i] = make_float4(0.f, 0.f, 0.f, 0.f);
    float mval = -1e30f, lval = 0.0f;

    const unsigned short* kbase = kb + (size_t)bh * T_ * HS_;
    const unsigned short* vbase = vb + (size_t)bh * T_ * HS_;

    const int ntile = (r0 + 128) / 64;
    const int lr  = tid >> 1;              // 0..63
    const int lce = (tid & 1) * 32;        // element offset 0 or 32

    for (int kt = 0; kt < ntile; kt++) {
        __syncthreads();
        {
            const unsigned short* kp = kbase + (size_t)(kt * 64 + lr) * HS_ + lce;
            const unsigned short* vp = vbase + (size_t)(kt * 64 + lr) * HS_ + lce;
#pragma unroll
            for (int j = 0; j < 4; j++) {
                U8 u; u.v = *(const uint4*)(kp + 8 * j);
                Ks[lr*16 + (lce>>2) + 2*j  ] = make_float4(bf2f(u.s[0]), bf2f(u.s[1]),
                                                           bf2f(u.s[2]), bf2f(u.s[3]));
                Ks[lr*16 + (lce>>2) + 2*j+1] = make_float4(bf2f(u.s[4]), bf2f(u.s[5]),
                                                           bf2f(u.s[6]), bf2f(u.s[7]));
                U8 w; w.v = *(const uint4*)(vp + 8 * j);
                Vs[lr*16 + (lce>>2) + 2*j  ] = make_float4(bf2f(w.s[0]), bf2f(w.s[1]),
                                                           bf2f(w.s[2]), bf2f(w.s[3]));
                Vs[lr*16 + (lce>>2) + 2*j+1] = make_float4(bf2f(w.s[4]), bf2f(w.s[5]),
                                                           bf2f(w.s[6]), bf2f(w.s[7]));
            }
        }
        __syncthreads();

        const int kmax = min(64, tq - kt * 64 + 1);   // valid rows this tile
        for (int kk = 0; kk < kmax; kk++) {
            float sa0 = 0.f, sa1 = 0.f, sa2 = 0.f, sa3 = 0.f;
#pragma unroll
            for (int i = 0; i < 16; i += 4) {
                float4 k0v = Ks[kk * 16 + i + 0];
                float4 k1v = Ks[kk * 16 + i + 1];
                float4 k2v = Ks[kk * 16 + i + 2];
                float4 k3v = Ks[kk * 16 + i + 3];
                sa0 += qf[i+0].x*k0v.x + qf[i+0].y*k0v.y + qf[i+0].z*k0v.z + qf[i+0].w*k0v.w;
                sa1 += qf[i+1].x*k1v.x + qf[i+1].y*k1v.y + qf[i+1].z*k1v.z + qf[i+1].w*k1v.w;
                sa2 += qf[i+2].x*k2v.x + qf[i+2].y*k2v.y + qf[i+2].z*k2v.z + qf[i+2].w*k2v.w;
                sa3 += qf[i+3].x*k3v.x + qf[i+3].y*k3v.y + qf[i+3].z*k3v.z + qf[i+3].w*k3v.w;
            }
            const float s = (sa0 + sa1) + (sa2 + sa3);
            const float mnew  = fmaxf(mval, s);
            const float alpha = __expf(mval - mnew);
            const float pv    = __expf(s - mnew);
            lval = lval * alpha + pv;
#pragma unroll
            for (int i = 0; i < 16; i++) {
                float4 vv = Vs[kk * 16 + i];
                of[i].x = of[i].x * alpha + pv * vv.x;
                of[i].y = of[i].y * alpha + pv * vv.y;
                of[i].z = of[i].z * alpha + pv * vv.z;
                of[i].w = of[i].w * alpha + pv * vv.w;
            }
            mval = mnew;
        }
    }

    const float invl = 1.0f / lval;
    unsigned short* yrow = yb + ((size_t)b * T_ + tq) * N_ + h * HS_;
#pragma unroll
    for (int i = 0; i < 16; i++) {
        ushort4 st;
        st.x = f2bf(of[i].x * invl);
        st.y = f2bf(of[i].y * invl);
        st.z = f2bf(of[i].z * invl);
        st.w = f2bf(of[i].w * invl);
        *(ushort4*)(yrow + 4 * i) = st;
    }
}

// ---------------------------------------------------------------------------
// Kernel 4: output projection. out = y @ wc + bc. Dual-dtype W/bias/out.
// grid = (16, 64), block = 256
// ---------------------------------------------------------------------------
__global__ __launch_bounds__(256) void out_gemm(
    const unsigned short* __restrict__ A,   // y bf16 [M,1024] (internal)
    const void* __restrict__ W,             // wc [1024,1024]
    const void* __restrict__ bias,          // bc [1024]
    void* __restrict__ out,                 // [M,1024], dtype per flag
    const int* __restrict__ flagp)
{
    const bool f32 = (*flagp != 0);
    __shared__ float As[32][64];
    __shared__ float Ws[32][64];

    const int tid = threadIdx.x;
    const int tx = tid & 15, ty = tid >> 4;
    const int m0 = blockIdx.y * 64, n0 = blockIdx.x * 64;

    const int ar  = tid >> 2;
    const int akc = (tid & 3) * 8;
    const int wkr = tid >> 3;
    const int wnc = (tid & 7) * 8;

    float acc[4][4] = {};

    for (int k0 = 0; k0 < 1024; k0 += 32) {
        float av8[8], wv8[8];
        {
            U8 a; a.v = *(const uint4*)(A + (size_t)(m0 + ar) * 1024 + k0 + akc);
#pragma unroll
            for (int j = 0; j < 8; j++) av8[j] = bf2f(a.s[j]);
        }
        const size_t woff = (size_t)(k0 + wkr) * 1024 + n0 + wnc;
        if (f32) {
            const float4* pw = (const float4*)((const float*)W + woff);
            float4 w0 = pw[0], w1 = pw[1];
            wv8[0]=w0.x; wv8[1]=w0.y; wv8[2]=w0.z; wv8[3]=w0.w;
            wv8[4]=w1.x; wv8[5]=w1.y; wv8[6]=w1.z; wv8[7]=w1.w;
        } else {
            U8 w; w.v = *(const uint4*)((const unsigned short*)W + woff);
#pragma unroll
            for (int j = 0; j < 8; j++) wv8[j] = bf2f(w.s[j]);
        }
        __syncthreads();
#pragma unroll
        for (int j = 0; j < 8; j++) As[akc + j][ar] = av8[j];
#pragma unroll
        for (int j = 0; j < 8; j++) Ws[wkr][wnc + j] = wv8[j];
        __syncthreads();
#pragma unroll 8
        for (int kk = 0; kk < 32; kk++) {
            const float4 av  = *(const float4*)&As[kk][ty * 4];
            const float4 bv4 = *(const float4*)&Ws[kk][tx * 4];
            const float a4[4] = {av.x, av.y, av.z, av.w};
            const float b4[4] = {bv4.x, bv4.y, bv4.z, bv4.w};
#pragma unroll
            for (int i = 0; i < 4; i++)
#pragma unroll
                for (int j = 0; j < 4; j++) acc[i][j] += a4[i] * b4[j];
        }
    }

    const int n = n0 + tx * 4;
    float bz[4];
#pragma unroll
    for (int j = 0; j < 4; j++)
        bz[j] = f32 ? ((const float*)bias)[n + j]
                    : bf2f(((const unsigned short*)bias)[n + j]);
#pragma unroll
    for (int i = 0; i < 4; i++) {
        const int m = m0 + ty * 4 + i;
        if (f32) {
            float4 r;
            r.x = acc[i][0] + bz[0];
            r.y = acc[i][1] + bz[1];
            r.z = acc[i][2] + bz[2];
            r.w = acc[i][3] + bz[3];
            *(float4*)((float*)out + (size_t)m * 1024 + n) = r;
        } else {
            ushort4 st;
            st.x = f2bf(acc[i][0] + bz[0]);
            st.y = f2bf(acc[i][1] + bz[1]);
            st.z = f2bf(acc[i][2] + bz[2]);
            st.w = f2bf(acc[i][3] + bz[3]);
            *(ushort4*)((unsigned short*)out + (size_t)m * 1024 + n) = st;
        }
    }
}

// ---------------------------------------------------------------------------
extern "C" void kernel_launch(void* const* d_in, const int* in_sizes, int n_in,
                              void* d_out, int out_size, void* d_ws, size_t ws_size,
                              hipStream_t stream) {
    // ws layout: [0..255] flag area, then 4 bf16 intermediates of 4M elems each
    int* flag = (int*)d_ws;
    unsigned short* qb = (unsigned short*)d_ws + 128;
    unsigned short* kb = qb + (size_t)4194304;
    unsigned short* vb = qb + (size_t)8388608;
    unsigned short* yb = qb + (size_t)12582912;

    detect_kernel<<<1, 256, 0, stream>>>((const unsigned short*)d_in[0], flag);
    qkv_gemm<<<dim3(N_ / 64, M_ / 64, 3), 256, 0, stream>>>(
        d_in[0], d_in[1], d_in[2], d_in[3], d_in[4], d_in[5], d_in[6],
        qb, kb, vb, flag);
    rope_kernel<<<(B_ * H_ * T_ * 32) / 256, 256, 0, stream>>>(qb, kb);
    attn_kernel<<<dim3(B_ * H_, T_ / 128), 128, 0, stream>>>(qb, kb, vb, yb);
    out_gemm<<<dim3(16, 64), 256, 0, stream>>>(yb, d_in[7], d_in[8], d_out, flag);
}

// Round 4
// 1050.491 us; speedup vs baseline: 2.4320x; 2.4320x over previous
//
#include <hip/hip_runtime.h>

#define B_  2
#define T_  2048
#define C_  1024
#define H_  16
#define HS_ 64
#define M_  4096
#define N_  1024
#define K_  1024

typedef float floatx4 __attribute__((ext_vector_type(4)));
typedef short bf16x8  __attribute__((ext_vector_type(8)));

__device__ __forceinline__ float bf2f(unsigned short u) {
    return __uint_as_float(((unsigned int)u) << 16);
}
__device__ __forceinline__ unsigned short f2bf(float f) {
    unsigned int u = __float_as_uint(f);
    return (unsigned short)((u + 0x7fffu + ((u >> 16) & 1u)) >> 16);
}
__device__ __forceinline__ unsigned int pack2(float a, float b) {
    return (unsigned int)f2bf(a) | ((unsigned int)f2bf(b) << 16);
}
__device__ __forceinline__ void bf8_to_f(uint4 u, float4& a, float4& b) {
    a.x = bf2f((unsigned short)(u.x & 0xffff)); a.y = bf2f((unsigned short)(u.x >> 16));
    a.z = bf2f((unsigned short)(u.y & 0xffff)); a.w = bf2f((unsigned short)(u.y >> 16));
    b.x = bf2f((unsigned short)(u.z & 0xffff)); b.y = bf2f((unsigned short)(u.z >> 16));
    b.z = bf2f((unsigned short)(u.w & 0xffff)); b.w = bf2f((unsigned short)(u.w >> 16));
}

// ---------------------------------------------------------------------------
// Kernel 1: QKV projection via MFMA. out[p] = x @ W[p] + b[p] -> bf16 [B,H,T,HS]
// 128x128 block tile, BK=32, 4 waves (each 64x64). grid = (8, 32, 3), block 256.
// ---------------------------------------------------------------------------
__global__ __launch_bounds__(256) void qkv_gemm(
    const float* __restrict__ x,
    const float* __restrict__ wq, const float* __restrict__ bq,
    const float* __restrict__ wk, const float* __restrict__ bk,
    const float* __restrict__ wv, const float* __restrict__ bv,
    unsigned short* __restrict__ qb, unsigned short* __restrict__ kb,
    unsigned short* __restrict__ vb)
{
    const int p = blockIdx.z;
    const float* W    = (p == 0) ? wq : (p == 1) ? wk : wv;
    const float* bias = (p == 0) ? bq : (p == 1) ? bk : bv;
    unsigned short* out = (p == 0) ? qb : (p == 1) ? kb : vb;

    __shared__ unsigned short As[128 * 40];   // [m][k], stride 40 bf16 (pad)
    __shared__ unsigned short Bs[128 * 40];   // [n][k] (W transposed), stride 40

    const int tid  = threadIdx.x;
    const int lane = tid & 63;
    const int wave = tid >> 6;
    const int wr = wave >> 1, wc = wave & 1;
    const int m0 = blockIdx.y * 128, n0 = blockIdx.x * 128;

    const int ar  = tid >> 1;            // 0..127 A row
    const int akh = (tid & 1) * 16;      // A k offset (16 elems)
    const int bn  = tid & 127;           // 0..127 B col (n)
    const int bkg = (tid >> 7) * 16;     // B k offset (16 elems)

    const int fr = lane & 15;            // fragment row
    const int fk = (lane >> 4) * 8;      // fragment k base

    floatx4 acc[4][4];
#pragma unroll
    for (int i = 0; i < 4; i++)
#pragma unroll
        for (int j = 0; j < 4; j++) acc[i][j] = (floatx4){0.f, 0.f, 0.f, 0.f};

    for (int k0 = 0; k0 < K_; k0 += 32) {
        // global loads (fp32)
        const float4* ap = (const float4*)(x + (size_t)(m0 + ar) * K_ + k0 + akh);
        const float4 a0 = ap[0], a1 = ap[1], a2 = ap[2], a3 = ap[3];
        float wv16[16];
#pragma unroll
        for (int i = 0; i < 16; i++)
            wv16[i] = W[(size_t)(k0 + bkg + i) * N_ + n0 + bn];

        __syncthreads();
        {
            uint4 u0, u1;
            u0.x = pack2(a0.x, a0.y); u0.y = pack2(a0.z, a0.w);
            u0.z = pack2(a1.x, a1.y); u0.w = pack2(a1.z, a1.w);
            u1.x = pack2(a2.x, a2.y); u1.y = pack2(a2.z, a2.w);
            u1.z = pack2(a3.x, a3.y); u1.w = pack2(a3.z, a3.w);
            *(uint4*)&As[ar * 40 + akh]     = u0;
            *(uint4*)&As[ar * 40 + akh + 8] = u1;
            uint4 b0, b1;
            b0.x = pack2(wv16[0],  wv16[1]);  b0.y = pack2(wv16[2],  wv16[3]);
            b0.z = pack2(wv16[4],  wv16[5]);  b0.w = pack2(wv16[6],  wv16[7]);
            b1.x = pack2(wv16[8],  wv16[9]);  b1.y = pack2(wv16[10], wv16[11]);
            b1.z = pack2(wv16[12], wv16[13]); b1.w = pack2(wv16[14], wv16[15]);
            *(uint4*)&Bs[bn * 40 + bkg]     = b0;
            *(uint4*)&Bs[bn * 40 + bkg + 8] = b1;
        }
        __syncthreads();

        bf16x8 af[4], bfr[4];
#pragma unroll
        for (int i = 0; i < 4; i++)
            af[i] = *(const bf16x8*)&As[(wr * 64 + i * 16 + fr) * 40 + fk];
#pragma unroll
        for (int j = 0; j < 4; j++)
            bfr[j] = *(const bf16x8*)&Bs[(wc * 64 + j * 16 + fr) * 40 + fk];
#pragma unroll
        for (int i = 0; i < 4; i++)
#pragma unroll
            for (int j = 0; j < 4; j++)
                acc[i][j] = __builtin_amdgcn_mfma_f32_16x16x32_bf16(
                    af[i], bfr[j], acc[i][j], 0, 0, 0);
    }

    // epilogue: bias + scatter bf16 into [B,H,T,HS]
    const int rbase = (lane >> 4) * 4;
#pragma unroll
    for (int j = 0; j < 4; j++) {
        const int col = n0 + wc * 64 + j * 16 + fr;
        const float bz = bias[col];
        const int h = col >> 6, d = col & 63;
#pragma unroll
        for (int i = 0; i < 4; i++) {
#pragma unroll
            for (int pr = 0; pr < 4; pr++) {
                const int row = m0 + wr * 64 + i * 16 + rbase + pr;
                const int bb = row >> 11;          // / 2048
                const int tt = row & 2047;
                out[(((size_t)(bb * H_ + h)) * T_ + tt) * HS_ + d] =
                    f2bf(acc[i][j][pr] + bz);
            }
        }
    }
}

// ---------------------------------------------------------------------------
// Kernel 2: RoPE in-place on bf16 q/k [B,H,T,HS].
// ---------------------------------------------------------------------------
__global__ __launch_bounds__(256) void rope_kernel(unsigned short* __restrict__ qb,
                                                   unsigned short* __restrict__ kb)
{
    const int idx = blockIdx.x * 256 + threadIdx.x;
    const int d  = idx & 31;
    const int t  = (idx >> 5) & (T_ - 1);
    const int bh = idx >> 16;            // T_*32 == 65536
    const size_t base = ((size_t)bh * T_ + t) * HS_;

    const float inv_freq = powf(10000.0f, -(float)d * (1.0f / 32.0f));
    float s, c;
    sincosf((float)t * inv_freq, &s, &c);

    {
        float x1 = bf2f(qb[base + d]), x2 = bf2f(qb[base + d + 32]);
        qb[base + d]      = f2bf(x1 * c - x2 * s);
        qb[base + d + 32] = f2bf(x2 * c + x1 * s);
    }
    {
        float x1 = bf2f(kb[base + d]), x2 = bf2f(kb[base + d + 32]);
        kb[base + d]      = f2bf(x1 * c - x2 * s);
        kb[base + d + 32] = f2bf(x2 * c + x1 * s);
    }
}

// ---------------------------------------------------------------------------
// Kernel 3: causal flash attention. 4 threads per q-row (16 dims each),
// 64 q-rows per block (256 thr), K/V 64-row fp32 tiles in LDS.
// grid = (B*H=32, T/64=32), block 256.
// ---------------------------------------------------------------------------
__global__ __launch_bounds__(256) void attn_kernel(
    const unsigned short* __restrict__ qb, const unsigned short* __restrict__ kb,
    const unsigned short* __restrict__ vb, unsigned short* __restrict__ yb)
{
    __shared__ float Ks[64 * 64];
    __shared__ float Vs[64 * 64];

    const int bh = blockIdx.x;             // b*H + h
    const int b = bh >> 4, h = bh & 15;
    const int r0 = blockIdx.y * 64;
    const int tid = threadIdx.x;
    const int row = tid >> 2, g = tid & 3; // 4 threads per q-row
    const int tq = r0 + row;

    // load this thread's 16 q dims, pre-scaled by 1/sqrt(64)
    float4 qf[4];
    {
        const unsigned short* qrow = qb + ((size_t)bh * T_ + tq) * HS_ + g * 16;
        uint4 u0 = *(const uint4*)qrow;
        uint4 u1 = *(const uint4*)(qrow + 8);
        bf8_to_f(u0, qf[0], qf[1]);
        bf8_to_f(u1, qf[2], qf[3]);
#pragma unroll
        for (int i = 0; i < 4; i++) {
            qf[i].x *= 0.125f; qf[i].y *= 0.125f;
            qf[i].z *= 0.125f; qf[i].w *= 0.125f;
        }
    }
    float4 of[4];
#pragma unroll
    for (int i = 0; i < 4; i++) of[i] = make_float4(0.f, 0.f, 0.f, 0.f);
    float mval = -1e30f, lval = 0.0f;

    const unsigned short* kbase = kb + (size_t)bh * T_ * HS_;
    const unsigned short* vbase = vb + (size_t)bh * T_ * HS_;

    const int ntile = blockIdx.y + 1;
    for (int kt = 0; kt < ntile; kt++) {
        __syncthreads();
#pragma unroll
        for (int jj = 0; jj < 2; jj++) {
            const int idx = tid + jj * 256;          // 0..511
            const int kr = idx >> 3, c8 = (idx & 7) * 8;
            uint4 u = *(const uint4*)(kbase + (size_t)(kt * 64 + kr) * HS_ + c8);
            float4 f0, f1; bf8_to_f(u, f0, f1);
            *(float4*)&Ks[kr * 64 + c8]     = f0;
            *(float4*)&Ks[kr * 64 + c8 + 4] = f1;
            uint4 w = *(const uint4*)(vbase + (size_t)(kt * 64 + kr) * HS_ + c8);
            float4 g0, g1; bf8_to_f(w, g0, g1);
            *(float4*)&Vs[kr * 64 + c8]     = g0;
            *(float4*)&Vs[kr * 64 + c8 + 4] = g1;
        }
        __syncthreads();

        const int kmax = (kt == blockIdx.y) ? (row + 1) : 64;
        for (int kk = 0; kk < kmax; kk++) {
            const float* kp = &Ks[kk * 64 + g * 16];
            const float4 k0 = *(const float4*)(kp);
            const float4 k1 = *(const float4*)(kp + 4);
            const float4 k2 = *(const float4*)(kp + 8);
            const float4 k3 = *(const float4*)(kp + 12);
            float pa = qf[0].x*k0.x + qf[0].y*k0.y + qf[0].z*k0.z + qf[0].w*k0.w
                     + qf[1].x*k1.x + qf[1].y*k1.y + qf[1].z*k1.z + qf[1].w*k1.w;
            float pb = qf[2].x*k2.x + qf[2].y*k2.y + qf[2].z*k2.z + qf[2].w*k2.w
                     + qf[3].x*k3.x + qf[3].y*k3.y + qf[3].z*k3.z + qf[3].w*k3.w;
            float p = pa + pb;
            p += __shfl_xor(p, 1);
            p += __shfl_xor(p, 2);
            const float mnew  = fmaxf(mval, p);
            const float alpha = __expf(mval - mnew);
            const float pw    = __expf(p - mnew);
            lval = lval * alpha + pw;
            const float* vp = &Vs[kk * 64 + g * 16];
            const float4 v0 = *(const float4*)(vp);
            const float4 v1 = *(const float4*)(vp + 4);
            const float4 v2 = *(const float4*)(vp + 8);
            const float4 v3 = *(const float4*)(vp + 12);
            of[0].x = of[0].x*alpha + pw*v0.x; of[0].y = of[0].y*alpha + pw*v0.y;
            of[0].z = of[0].z*alpha + pw*v0.z; of[0].w = of[0].w*alpha + pw*v0.w;
            of[1].x = of[1].x*alpha + pw*v1.x; of[1].y = of[1].y*alpha + pw*v1.y;
            of[1].z = of[1].z*alpha + pw*v1.z; of[1].w = of[1].w*alpha + pw*v1.w;
            of[2].x = of[2].x*alpha + pw*v2.x; of[2].y = of[2].y*alpha + pw*v2.y;
            of[2].z = of[2].z*alpha + pw*v2.z; of[2].w = of[2].w*alpha + pw*v2.w;
            of[3].x = of[3].x*alpha + pw*v3.x; of[3].y = of[3].y*alpha + pw*v3.y;
            of[3].z = of[3].z*alpha + pw*v3.z; of[3].w = of[3].w*alpha + pw*v3.w;
            mval = mnew;
        }
    }

    const float invl = 1.0f / lval;
    unsigned short* yrow = yb + ((size_t)b * T_ + tq) * N_ + h * HS_ + g * 16;
    uint4 o0, o1;
    o0.x = pack2(of[0].x*invl, of[0].y*invl); o0.y = pack2(of[0].z*invl, of[0].w*invl);
    o0.z = pack2(of[1].x*invl, of[1].y*invl); o0.w = pack2(of[1].z*invl, of[1].w*invl);
    o1.x = pack2(of[2].x*invl, of[2].y*invl); o1.y = pack2(of[2].z*invl, of[2].w*invl);
    o1.z = pack2(of[3].x*invl, of[3].y*invl); o1.w = pack2(of[3].z*invl, of[3].w*invl);
    *(uint4*)yrow       = o0;
    *(uint4*)(yrow + 8) = o1;
}

// ---------------------------------------------------------------------------
// Kernel 4: output projection via MFMA. out = y @ wc + bc, fp32 out.
// grid = (8, 32), block 256.
// ---------------------------------------------------------------------------
__global__ __launch_bounds__(256) void out_gemm(
    const unsigned short* __restrict__ A,   // yb bf16 [4096][1024]
    const float* __restrict__ W,            // wc fp32 [1024][1024]
    const float* __restrict__ bias,         // bc fp32 [1024]
    float* __restrict__ out)                // fp32 [4096][1024]
{
    __shared__ unsigned short As[128 * 40];
    __shared__ unsigned short Bs[128 * 40];

    const int tid  = threadIdx.x;
    const int lane = tid & 63;
    const int wave = tid >> 6;
    const int wr = wave >> 1, wc = wave & 1;
    const int m0 = blockIdx.y * 128, n0 = blockIdx.x * 128;

    const int ar  = tid >> 1;
    const int akh = (tid & 1) * 16;
    const int bn  = tid & 127;
    const int bkg = (tid >> 7) * 16;

    const int fr = lane & 15;
    const int fk = (lane >> 4) * 8;

    floatx4 acc[4][4];
#pragma unroll
    for (int i = 0; i < 4; i++)
#pragma unroll
        for (int j = 0; j < 4; j++) acc[i][j] = (floatx4){0.f, 0.f, 0.f, 0.f};

    for (int k0 = 0; k0 < K_; k0 += 32) {
        const uint4* ap = (const uint4*)(A + (size_t)(m0 + ar) * K_ + k0 + akh);
        const uint4 a0 = ap[0], a1 = ap[1];          // 16 bf16, no convert
        float wv16[16];
#pragma unroll
        for (int i = 0; i < 16; i++)
            wv16[i] = W[(size_t)(k0 + bkg + i) * N_ + n0 + bn];

        __syncthreads();
        *(uint4*)&As[ar * 40 + akh]     = a0;
        *(uint4*)&As[ar * 40 + akh + 8] = a1;
        {
            uint4 b0, b1;
            b0.x = pack2(wv16[0],  wv16[1]);  b0.y = pack2(wv16[2],  wv16[3]);
            b0.z = pack2(wv16[4],  wv16[5]);  b0.w = pack2(wv16[6],  wv16[7]);
            b1.x = pack2(wv16[8],  wv16[9]);  b1.y = pack2(wv16[10], wv16[11]);
            b1.z = pack2(wv16[12], wv16[13]); b1.w = pack2(wv16[14], wv16[15]);
            *(uint4*)&Bs[bn * 40 + bkg]     = b0;
            *(uint4*)&Bs[bn * 40 + bkg + 8] = b1;
        }
        __syncthreads();

        bf16x8 af[4], bfr[4];
#pragma unroll
        for (int i = 0; i < 4; i++)
            af[i] = *(const bf16x8*)&As[(wr * 64 + i * 16 + fr) * 40 + fk];
#pragma unroll
        for (int j = 0; j < 4; j++)
            bfr[j] = *(const bf16x8*)&Bs[(wc * 64 + j * 16 + fr) * 40 + fk];
#pragma unroll
        for (int i = 0; i < 4; i++)
#pragma unroll
            for (int j = 0; j < 4; j++)
                acc[i][j] = __builtin_amdgcn_mfma_f32_16x16x32_bf16(
                    af[i], bfr[j], acc[i][j], 0, 0, 0);
    }

    const int rbase = (lane >> 4) * 4;
#pragma unroll
    for (int j = 0; j < 4; j++) {
        const int col = n0 + wc * 64 + j * 16 + fr;
        const float bz = bias[col];
#pragma unroll
        for (int i = 0; i < 4; i++) {
#pragma unroll
            for (int pr = 0; pr < 4; pr++) {
                const int row = m0 + wr * 64 + i * 16 + rbase + pr;
                out[(size_t)row * N_ + col] = acc[i][j][pr] + bz;
            }
        }
    }
}

// ---------------------------------------------------------------------------
extern "C" void kernel_launch(void* const* d_in, const int* in_sizes, int n_in,
                              void* d_out, int out_size, void* d_ws, size_t ws_size,
                              hipStream_t stream) {
    const float* x  = (const float*)d_in[0];
    const float* wq = (const float*)d_in[1];
    const float* bq = (const float*)d_in[2];
    const float* wk = (const float*)d_in[3];
    const float* bk = (const float*)d_in[4];
    const float* wv = (const float*)d_in[5];
    const float* bv = (const float*)d_in[6];
    const float* wc = (const float*)d_in[7];
    const float* bc = (const float*)d_in[8];
    float* out = (float*)d_out;

    // bf16 intermediates: 4 x 4M elements = 32 MB
    unsigned short* qb = (unsigned short*)d_ws;
    unsigned short* kb = qb + (size_t)4194304;
    unsigned short* vb = qb + (size_t)8388608;
    unsigned short* yb = qb + (size_t)12582912;

    qkv_gemm<<<dim3(8, 32, 3), 256, 0, stream>>>(
        x, wq, bq, wk, bk, wv, bv, qb, kb, vb);
    rope_kernel<<<(B_ * H_ * T_ * 32) / 256, 256, 0, stream>>>(qb, kb);
    attn_kernel<<<dim3(32, 32), 256, 0, stream>>>(qb, kb, vb, yb);
    out_gemm<<<dim3(8, 32), 256, 0, stream>>>(yb, wc, bc, out);
}

// Round 5
// 251.574 us; speedup vs baseline: 10.1552x; 4.1757x over previous
//
#include <hip/hip_runtime.h>

#define B_  2
#define T_  2048
#define C_  1024
#define H_  16
#define HS_ 64
#define M_  4096
#define N_  1024
#define K_  1024

typedef float floatx4 __attribute__((ext_vector_type(4)));
typedef short bf16x8  __attribute__((ext_vector_type(8)));

__device__ __forceinline__ float bf2f(unsigned short u) {
    return __uint_as_float(((unsigned int)u) << 16);
}
__device__ __forceinline__ unsigned short f2bf(float f) {
    unsigned int u = __float_as_uint(f);
    return (unsigned short)((u + 0x7fffu + ((u >> 16) & 1u)) >> 16);
}
__device__ __forceinline__ unsigned int pack2(float a, float b) {
    return (unsigned int)f2bf(a) | ((unsigned int)f2bf(b) << 16);
}

// ---------------------------------------------------------------------------
// Kernel 1: QKV projection via MFMA. q,k -> bf16 [B,H,T,HS]; v -> TRANSPOSED
// bf16 [B,H,HS,T] (ready as PV's A-operand). grid = (8, 32, 3), block 256.
// ---------------------------------------------------------------------------
__global__ __launch_bounds__(256) void qkv_gemm(
    const float* __restrict__ x,
    const float* __restrict__ wq, const float* __restrict__ bq,
    const float* __restrict__ wk, const float* __restrict__ bk,
    const float* __restrict__ wv, const float* __restrict__ bv,
    unsigned short* __restrict__ qb, unsigned short* __restrict__ kb,
    unsigned short* __restrict__ vb)
{
    const int p = blockIdx.z;
    const float* W    = (p == 0) ? wq : (p == 1) ? wk : wv;
    const float* bias = (p == 0) ? bq : (p == 1) ? bk : bv;
    unsigned short* out = (p == 0) ? qb : (p == 1) ? kb : vb;

    __shared__ unsigned short As[128 * 40];   // [m][k], stride 40 bf16 (pad)
    __shared__ unsigned short Bs[128 * 40];   // [n][k] (W transposed), stride 40

    const int tid  = threadIdx.x;
    const int lane = tid & 63;
    const int wave = tid >> 6;
    const int wr = wave >> 1, wc = wave & 1;
    const int m0 = blockIdx.y * 128, n0 = blockIdx.x * 128;

    const int ar  = tid >> 1;            // 0..127 A row
    const int akh = (tid & 1) * 16;      // A k offset (16 elems)
    const int bn  = tid & 127;           // 0..127 B col (n)
    const int bkg = (tid >> 7) * 16;     // B k offset (16 elems)

    const int fr = lane & 15;            // fragment row
    const int fk = (lane >> 4) * 8;      // fragment k base

    floatx4 acc[4][4];
#pragma unroll
    for (int i = 0; i < 4; i++)
#pragma unroll
        for (int j = 0; j < 4; j++) acc[i][j] = (floatx4){0.f, 0.f, 0.f, 0.f};

    for (int k0 = 0; k0 < K_; k0 += 32) {
        const float4* ap = (const float4*)(x + (size_t)(m0 + ar) * K_ + k0 + akh);
        const float4 a0 = ap[0], a1 = ap[1], a2 = ap[2], a3 = ap[3];
        float wv16[16];
#pragma unroll
        for (int i = 0; i < 16; i++)
            wv16[i] = W[(size_t)(k0 + bkg + i) * N_ + n0 + bn];

        __syncthreads();
        {
            uint4 u0, u1;
            u0.x = pack2(a0.x, a0.y); u0.y = pack2(a0.z, a0.w);
            u0.z = pack2(a1.x, a1.y); u0.w = pack2(a1.z, a1.w);
            u1.x = pack2(a2.x, a2.y); u1.y = pack2(a2.z, a2.w);
            u1.z = pack2(a3.x, a3.y); u1.w = pack2(a3.z, a3.w);
            *(uint4*)&As[ar * 40 + akh]     = u0;
            *(uint4*)&As[ar * 40 + akh + 8] = u1;
            uint4 b0, b1;
            b0.x = pack2(wv16[0],  wv16[1]);  b0.y = pack2(wv16[2],  wv16[3]);
            b0.z = pack2(wv16[4],  wv16[5]);  b0.w = pack2(wv16[6],  wv16[7]);
            b1.x = pack2(wv16[8],  wv16[9]);  b1.y = pack2(wv16[10], wv16[11]);
            b1.z = pack2(wv16[12], wv16[13]); b1.w = pack2(wv16[14], wv16[15]);
            *(uint4*)&Bs[bn * 40 + bkg]     = b0;
            *(uint4*)&Bs[bn * 40 + bkg + 8] = b1;
        }
        __syncthreads();

        bf16x8 af[4], bfr[4];
#pragma unroll
        for (int i = 0; i < 4; i++)
            af[i] = *(const bf16x8*)&As[(wr * 64 + i * 16 + fr) * 40 + fk];
#pragma unroll
        for (int j = 0; j < 4; j++)
            bfr[j] = *(const bf16x8*)&Bs[(wc * 64 + j * 16 + fr) * 40 + fk];
#pragma unroll
        for (int i = 0; i < 4; i++)
#pragma unroll
            for (int j = 0; j < 4; j++)
                acc[i][j] = __builtin_amdgcn_mfma_f32_16x16x32_bf16(
                    af[i], bfr[j], acc[i][j], 0, 0, 0);
    }

    // epilogue: bias + scatter bf16. q,k: [B,H,T,HS]; v: [B,H,HS,T] (transposed)
    const int rbase = (lane >> 4) * 4;
#pragma unroll
    for (int j = 0; j < 4; j++) {
        const int col = n0 + wc * 64 + j * 16 + fr;
        const float bz = bias[col];
        const int h = col >> 6, d = col & 63;
#pragma unroll
        for (int i = 0; i < 4; i++) {
#pragma unroll
            for (int pr = 0; pr < 4; pr++) {
                const int row = m0 + wr * 64 + i * 16 + rbase + pr;
                const int bb = row >> 11;          // / 2048
                const int tt = row & 2047;
                const size_t oidx = (p == 2)
                    ? (((size_t)(bb * H_ + h)) * HS_ + d) * T_ + tt
                    : (((size_t)(bb * H_ + h)) * T_ + tt) * HS_ + d;
                out[oidx] = f2bf(acc[i][j][pr] + bz);
            }
        }
    }
}

// ---------------------------------------------------------------------------
// Kernel 2: RoPE in-place on bf16 q/k [B,H,T,HS]. q also scaled by 1/8.
// ---------------------------------------------------------------------------
__global__ __launch_bounds__(256) void rope_kernel(unsigned short* __restrict__ qb,
                                                   unsigned short* __restrict__ kb)
{
    const int idx = blockIdx.x * 256 + threadIdx.x;
    const int d  = idx & 31;
    const int t  = (idx >> 5) & (T_ - 1);
    const int bh = idx >> 16;            // T_*32 == 65536
    const size_t base = ((size_t)bh * T_ + t) * HS_;

    const float inv_freq = powf(10000.0f, -(float)d * (1.0f / 32.0f));
    float s, c;
    sincosf((float)t * inv_freq, &s, &c);

    {   // q: rotate and fold in softmax scale 1/sqrt(64) = 0.125 (exact pow2)
        float x1 = bf2f(qb[base + d]), x2 = bf2f(qb[base + d + 32]);
        qb[base + d]      = f2bf((x1 * c - x2 * s) * 0.125f);
        qb[base + d + 32] = f2bf((x2 * c + x1 * s) * 0.125f);
    }
    {
        float x1 = bf2f(kb[base + d]), x2 = bf2f(kb[base + d + 32]);
        kb[base + d]      = f2bf(x1 * c - x2 * s);
        kb[base + d + 32] = f2bf(x2 * c + x1 * s);
    }
}

// ---------------------------------------------------------------------------
// Kernel 3: MFMA flash attention.
// Block = 4 waves = 64 q-rows (16/wave); K/V^T 64-key bf16 tiles in LDS
// (XOR-8 swizzled). S^T = mfma(K,Q) so softmax rows live per-lane; P via
// wave-private LDS round-trip; O^T = mfma(V^T, P). grid=(32,32), block 256.
// ---------------------------------------------------------------------------
__global__ __launch_bounds__(256) void attn_kernel(
    const unsigned short* __restrict__ qb, const unsigned short* __restrict__ kb,
    const unsigned short* __restrict__ vt, unsigned short* __restrict__ yb)
{
    __shared__ unsigned short Ks[64 * 64];      // [key][dim^sw]
    __shared__ unsigned short Vs[64 * 64];      // [dim][key^sw]  (V^T)
    __shared__ unsigned short Ps[4][16 * 64];   // per-wave [qrow][key^sw]

    const int bh = blockIdx.x;             // b*H + h
    const int b = bh >> 4, h = bh & 15;
    const int qt = blockIdx.y;
    const int r0 = qt * 64;
    const int tid  = threadIdx.x;
    const int lane = tid & 63;
    const int wave = tid >> 6;
    const int l4   = lane & 15;
    const int quad = lane >> 4;

    const int qrow_g = r0 + wave * 16 + l4;   // this lane's q row (n-index)

    // Q B-fragments (dims quad*8.. and +32), already scaled by 1/8 in rope
    bf16x8 qf[2];
    {
        const unsigned short* qp = qb + ((size_t)bh * T_ + qrow_g) * HS_ + quad * 8;
        qf[0] = *(const bf16x8*)(qp);
        qf[1] = *(const bf16x8*)(qp + 32);
    }

    floatx4 o[4];                              // O^T frags: vdim=16g+quad*4+reg, qrow=l4
#pragma unroll
    for (int g = 0; g < 4; g++) o[g] = (floatx4){0.f, 0.f, 0.f, 0.f};
    float m = -1e30f, l = 0.f;

    // staging assignment: 64 rows x 4 col-groups of 16
    const int srow = tid >> 2;
    const int sc16 = (tid & 3) * 16;
    const int ssw  = (srow & 7) * 8;
    const int psw  = (l4 & 7) * 8;

    for (int kt = 0; kt <= qt; kt++) {
        // global loads first (overlap with prior tile's compute drain)
        const unsigned short* kp = kb + ((size_t)bh * T_ + kt * 64 + srow) * HS_ + sc16;
        const uint4 k0 = *(const uint4*)kp;
        const uint4 k1 = *(const uint4*)(kp + 8);
        const unsigned short* vp = vt + ((size_t)(bh * 64 + srow)) * T_ + kt * 64 + sc16;
        const uint4 v0 = *(const uint4*)vp;
        const uint4 v1 = *(const uint4*)(vp + 8);

        __syncthreads();   // all waves done reading previous tile
        *(uint4*)&Ks[srow * 64 + ( sc16      ^ ssw)] = k0;
        *(uint4*)&Ks[srow * 64 + ((sc16 + 8) ^ ssw)] = k1;
        *(uint4*)&Vs[srow * 64 + ( sc16      ^ ssw)] = v0;
        *(uint4*)&Vs[srow * 64 + ((sc16 + 8) ^ ssw)] = v1;
        __syncthreads();

        // S^T[key][qrow]: 4 key-groups x (2 mfma over dims)
        floatx4 sf[4];
#pragma unroll
        for (int mg = 0; mg < 4; mg++) {
            const int key = mg * 16 + l4;
            const int ksw = (key & 7) * 8;
            const bf16x8 a0 = *(const bf16x8*)&Ks[key * 64 + ( (quad * 8)      ^ ksw)];
            const bf16x8 a1 = *(const bf16x8*)&Ks[key * 64 + (((quad * 8) + 32) ^ ksw)];
            floatx4 z = (floatx4){0.f, 0.f, 0.f, 0.f};
            z = __builtin_amdgcn_mfma_f32_16x16x32_bf16(a0, qf[0], z, 0, 0, 0);
            z = __builtin_amdgcn_mfma_f32_16x16x32_bf16(a1, qf[1], z, 0, 0, 0);
            sf[mg] = z;
        }

        // causal mask on diagonal tile: lane's sf[mg][r] has key=16mg+quad*4+r
        if (kt == qt) {
#pragma unroll
            for (int mg = 0; mg < 4; mg++)
#pragma unroll
                for (int r = 0; r < 4; r++)
                    if (kt * 64 + 16 * mg + quad * 4 + r > qrow_g)
                        sf[mg][r] = -1e30f;
        }

        // online softmax; all 16 in-lane values share qrow = l4
        float tm = sf[0][0];
#pragma unroll
        for (int mg = 0; mg < 4; mg++)
#pragma unroll
            for (int r = 0; r < 4; r++) tm = fmaxf(tm, sf[mg][r]);
        tm = fmaxf(tm, __shfl_xor(tm, 16));
        tm = fmaxf(tm, __shfl_xor(tm, 32));
        const float mnew  = fmaxf(m, tm);
        const float alpha = __expf(m - mnew);

        float p[4][4];
        float ps = 0.f;
#pragma unroll
        for (int mg = 0; mg < 4; mg++)
#pragma unroll
            for (int r = 0; r < 4; r++) {
                p[mg][r] = __expf(sf[mg][r] - mnew);
                ps += p[mg][r];
            }
        ps += __shfl_xor(ps, 16);
        ps += __shfl_xor(ps, 32);
        l = l * alpha + ps;
        m = mnew;
#pragma unroll
        for (int g = 0; g < 4; g++) {
            o[g][0] *= alpha; o[g][1] *= alpha;
            o[g][2] *= alpha; o[g][3] *= alpha;
        }

        // write P (bf16) to wave-private LDS: [qrow=l4][key ^ psw]
#pragma unroll
        for (int mg = 0; mg < 4; mg++) {
            const int kb4 = 16 * mg + quad * 4;
            const int off = ((kb4 & ~7) ^ psw) | (kb4 & 7);
            uint2 w;
            w.x = pack2(p[mg][0], p[mg][1]);
            w.y = pack2(p[mg][2], p[mg][3]);
            *(uint2*)&Ps[wave][l4 * 64 + off] = w;
        }

        // PV: O^T += mfma(V^T-frag, P-frag) ; contraction over 64 keys (2 steps)
        const bf16x8 pf0 = *(const bf16x8*)&Ps[wave][l4 * 64 + ( (quad * 8)       ^ psw)];
        const bf16x8 pf1 = *(const bf16x8*)&Ps[wave][l4 * 64 + (((quad * 8) + 32) ^ psw)];
#pragma unroll
        for (int g = 0; g < 4; g++) {
            const int vd  = g * 16 + l4;
            const int vsw = (vd & 7) * 8;   // == psw, kept explicit
            const bf16x8 va0 = *(const bf16x8*)&Vs[vd * 64 + ( (quad * 8)       ^ vsw)];
            const bf16x8 va1 = *(const bf16x8*)&Vs[vd * 64 + (((quad * 8) + 32) ^ vsw)];
            o[g] = __builtin_amdgcn_mfma_f32_16x16x32_bf16(va0, pf0, o[g], 0, 0, 0);
            o[g] = __builtin_amdgcn_mfma_f32_16x16x32_bf16(va1, pf1, o[g], 0, 0, 0);
        }
    }

    // epilogue: O^T lane holds (vdim = 16g+quad*4+reg, qrow = l4)
    const float invl = 1.f / l;
    unsigned short* yrow = yb + ((size_t)(b * T_ + qrow_g) * H_ + h) * HS_;
#pragma unroll
    for (int g = 0; g < 4; g++) {
        ushort4 st;
        st.x = f2bf(o[g][0] * invl);
        st.y = f2bf(o[g][1] * invl);
        st.z = f2bf(o[g][2] * invl);
        st.w = f2bf(o[g][3] * invl);
        *(ushort4*)&yrow[16 * g + quad * 4] = st;
    }
}

// ---------------------------------------------------------------------------
// Kernel 4: output projection via MFMA. out = y @ wc + bc, fp32 out.
// grid = (8, 32), block 256.
// ---------------------------------------------------------------------------
__global__ __launch_bounds__(256) void out_gemm(
    const unsigned short* __restrict__ A,   // yb bf16 [4096][1024]
    const float* __restrict__ W,            // wc fp32 [1024][1024]
    const float* __restrict__ bias,         // bc fp32 [1024]
    float* __restrict__ out)                // fp32 [4096][1024]
{
    __shared__ unsigned short As[128 * 40];
    __shared__ unsigned short Bs[128 * 40];

    const int tid  = threadIdx.x;
    const int lane = tid & 63;
    const int wave = tid >> 6;
    const int wr = wave >> 1, wc = wave & 1;
    const int m0 = blockIdx.y * 128, n0 = blockIdx.x * 128;

    const int ar  = tid >> 1;
    const int akh = (tid & 1) * 16;
    const int bn  = tid & 127;
    const int bkg = (tid >> 7) * 16;

    const int fr = lane & 15;
    const int fk = (lane >> 4) * 8;

    floatx4 acc[4][4];
#pragma unroll
    for (int i = 0; i < 4; i++)
#pragma unroll
        for (int j = 0; j < 4; j++) acc[i][j] = (floatx4){0.f, 0.f, 0.f, 0.f};

    for (int k0 = 0; k0 < K_; k0 += 32) {
        const uint4* ap = (const uint4*)(A + (size_t)(m0 + ar) * K_ + k0 + akh);
        const uint4 a0 = ap[0], a1 = ap[1];
        float wv16[16];
#pragma unroll
        for (int i = 0; i < 16; i++)
            wv16[i] = W[(size_t)(k0 + bkg + i) * N_ + n0 + bn];

        __syncthreads();
        *(uint4*)&As[ar * 40 + akh]     = a0;
        *(uint4*)&As[ar * 40 + akh + 8] = a1;
        {
            uint4 b0, b1;
            b0.x = pack2(wv16[0],  wv16[1]);  b0.y = pack2(wv16[2],  wv16[3]);
            b0.z = pack2(wv16[4],  wv16[5]);  b0.w = pack2(wv16[6],  wv16[7]);
            b1.x = pack2(wv16[8],  wv16[9]);  b1.y = pack2(wv16[10], wv16[11]);
            b1.z = pack2(wv16[12], wv16[13]); b1.w = pack2(wv16[14], wv16[15]);
            *(uint4*)&Bs[bn * 40 + bkg]     = b0;
            *(uint4*)&Bs[bn * 40 + bkg + 8] = b1;
        }
        __syncthreads();

        bf16x8 af[4], bfr[4];
#pragma unroll
        for (int i = 0; i < 4; i++)
            af[i] = *(const bf16x8*)&As[(wr * 64 + i * 16 + fr) * 40 + fk];
#pragma unroll
        for (int j = 0; j < 4; j++)
            bfr[j] = *(const bf16x8*)&Bs[(wc * 64 + j * 16 + fr) * 40 + fk];
#pragma unroll
        for (int i = 0; i < 4; i++)
#pragma unroll
            for (int j = 0; j < 4; j++)
                acc[i][j] = __builtin_amdgcn_mfma_f32_16x16x32_bf16(
                    af[i], bfr[j], acc[i][j], 0, 0, 0);
    }

    const int rbase = (lane >> 4) * 4;
#pragma unroll
    for (int j = 0; j < 4; j++) {
        const int col = n0 + wc * 64 + j * 16 + fr;
        const float bz = bias[col];
#pragma unroll
        for (int i = 0; i < 4; i++) {
#pragma unroll
            for (int pr = 0; pr < 4; pr++) {
                const int row = m0 + wr * 64 + i * 16 + rbase + pr;
                out[(size_t)row * N_ + col] = acc[i][j][pr] + bz;
            }
        }
    }
}

// ---------------------------------------------------------------------------
extern "C" void kernel_launch(void* const* d_in, const int* in_sizes, int n_in,
                              void* d_out, int out_size, void* d_ws, size_t ws_size,
                              hipStream_t stream) {
    const float* x  = (const float*)d_in[0];
    const float* wq = (const float*)d_in[1];
    const float* bq = (const float*)d_in[2];
    const float* wk = (const float*)d_in[3];
    const float* bk = (const float*)d_in[4];
    const float* wv = (const float*)d_in[5];
    const float* bv = (const float*)d_in[6];
    const float* wc = (const float*)d_in[7];
    const float* bc = (const float*)d_in[8];
    float* out = (float*)d_out;

    // bf16 intermediates: 4 x 4M elements = 32 MB
    unsigned short* qb = (unsigned short*)d_ws;            // [B,H,T,HS]
    unsigned short* kb = qb + (size_t)4194304;             // [B,H,T,HS]
    unsigned short* vb = qb + (size_t)8388608;             // [B,H,HS,T]  (V^T)
    unsigned short* yb = qb + (size_t)12582912;            // [B,T,C]

    qkv_gemm<<<dim3(8, 32, 3), 256, 0, stream>>>(
        x, wq, bq, wk, bk, wv, bv, qb, kb, vb);
    rope_kernel<<<(B_ * H_ * T_ * 32) / 256, 256, 0, stream>>>(qb, kb);
    attn_kernel<<<dim3(32, 32), 256, 0, stream>>>(qb, kb, vb, yb);
    out_gemm<<<dim3(8, 32), 256, 0, stream>>>(yb, wc, bc, out);
}

// Round 6
// 231.286 us; speedup vs baseline: 11.0460x; 1.0877x over previous
//
#include <hip/hip_runtime.h>

#define B_  2
#define T_  2048
#define C_  1024
#define H_  16
#define HS_ 64
#define M_  4096
#define N_  1024
#define K_  1024

typedef float floatx4 __attribute__((ext_vector_type(4)));
typedef short bf16x8  __attribute__((ext_vector_type(8)));

__device__ __forceinline__ float bf2f(unsigned short u) {
    return __uint_as_float(((unsigned int)u) << 16);
}
__device__ __forceinline__ unsigned short f2bf(float f) {
    unsigned int u = __float_as_uint(f);
    return (unsigned short)((u + 0x7fffu + ((u >> 16) & 1u)) >> 16);
}
__device__ __forceinline__ unsigned int pack2(float a, float b) {
    return (unsigned int)f2bf(a) | ((unsigned int)f2bf(b) << 16);
}
// async global->LDS, 16B per lane; lds dest = wave-uniform base + lane*16
__device__ __forceinline__ void async16(const unsigned short* g, unsigned short* l) {
    __builtin_amdgcn_global_load_lds(
        (const __attribute__((address_space(1))) unsigned int*)g,
        (__attribute__((address_space(3))) unsigned int*)l, 16, 0, 0);
}

// ---------------------------------------------------------------------------
// Prep 1: x fp32 -> bf16 [4096][1024]. grid 4096, block 256, 4 elems/thread.
// ---------------------------------------------------------------------------
__global__ __launch_bounds__(256) void convert_x(const float* __restrict__ x,
                                                 unsigned short* __restrict__ xb)
{
    const size_t i = ((size_t)blockIdx.x * 256 + threadIdx.x) * 4;
    const float4 v = *(const float4*)(x + i);
    ushort4 st;
    st.x = f2bf(v.x); st.y = f2bf(v.y); st.z = f2bf(v.z); st.w = f2bf(v.w);
    *(ushort4*)(xb + i) = st;
}

// ---------------------------------------------------------------------------
// Prep 2: transpose+convert weights: w fp32 [K][N] -> wT bf16 [N][K].
// grid (16,16,4): 64x64 tiles, z selects {wq,wk,wv,wc}. block 256.
// ---------------------------------------------------------------------------
__global__ __launch_bounds__(256) void transpose_w(
    const float* __restrict__ w0, const float* __restrict__ w1,
    const float* __restrict__ w2, const float* __restrict__ w3,
    unsigned short* __restrict__ wTall)
{
    __shared__ float tile[64][65];
    const int z = blockIdx.z;
    const float* w = (z == 0) ? w0 : (z == 1) ? w1 : (z == 2) ? w2 : w3;
    unsigned short* wT = wTall + ((size_t)z << 20);

    const int n0 = blockIdx.x * 64, k0 = blockIdx.y * 64;
    const int t = threadIdx.x;
    const int r = t >> 2, cq = (t & 3) * 16;

    const float4* src = (const float4*)(w + (size_t)(k0 + r) * N_ + n0 + cq);
    const float4 v0 = src[0], v1 = src[1], v2 = src[2], v3 = src[3];
    tile[r][cq+0]=v0.x; tile[r][cq+1]=v0.y; tile[r][cq+2]=v0.z; tile[r][cq+3]=v0.w;
    tile[r][cq+4]=v1.x; tile[r][cq+5]=v1.y; tile[r][cq+6]=v1.z; tile[r][cq+7]=v1.w;
    tile[r][cq+8]=v2.x; tile[r][cq+9]=v2.y; tile[r][cq+10]=v2.z; tile[r][cq+11]=v2.w;
    tile[r][cq+12]=v3.x; tile[r][cq+13]=v3.y; tile[r][cq+14]=v3.z; tile[r][cq+15]=v3.w;
    __syncthreads();

    const int rn = t >> 2, ck = (t & 3) * 16;
    unsigned int o[8];
#pragma unroll
    for (int ii = 0; ii < 8; ii++)
        o[ii] = pack2(tile[ck + 2*ii][rn], tile[ck + 2*ii + 1][rn]);
    unsigned short* dst = wT + (size_t)(n0 + rn) * K_ + k0 + ck;
    *(uint4*)dst       = make_uint4(o[0], o[1], o[2], o[3]);
    *(uint4*)(dst + 8) = make_uint4(o[4], o[5], o[6], o[7]);
}

// ---------------------------------------------------------------------------
// Kernel 1: fused QKV GEMM (m97-style). A = xb bf16 [M][K], B = wT bf16 [n][k].
// q,k -> [B,H,T,HS]; v -> transposed [B,H,HS,T]. grid (24, 32), block 256.
// ---------------------------------------------------------------------------
__global__ __launch_bounds__(256) void qkv_gemm(
    const unsigned short* __restrict__ xb, const unsigned short* __restrict__ wT,
    const float* __restrict__ bq, const float* __restrict__ bk,
    const float* __restrict__ bv,
    unsigned short* __restrict__ qb, unsigned short* __restrict__ kb,
    unsigned short* __restrict__ vb)
{
    __shared__ unsigned short As[128 * 32];   // [m][k], contiguous (async layout)
    __shared__ unsigned short Bs[128 * 32];   // [n][k]

    const int tid  = threadIdx.x;
    const int lane = tid & 63;
    const int wave = tid >> 6;
    const int p  = blockIdx.x >> 3;
    const int n0 = (blockIdx.x & 7) * 128;
    const int m0 = blockIdx.y * 128;
    const float* bias = (p == 0) ? bq : (p == 1) ? bk : bv;

    // staging addresses: lane l -> row l>>2, 8-elem chunk l&3 (matches lane*16B)
    const int lrow = lane >> 2, lch = (lane & 3) * 8;
    const unsigned short* ag0 = xb + (size_t)(m0 + wave * 32 + lrow) * K_ + lch;
    const unsigned short* ag1 = ag0 + (size_t)16 * K_;
    const unsigned short* wb  = wT + ((size_t)p << 20);
    const unsigned short* bg0 = wb + (size_t)(n0 + wave * 32 + lrow) * K_ + lch;
    const unsigned short* bg1 = bg0 + (size_t)16 * K_;
    unsigned short* lA0 = &As[(wave * 32) * 32];
    unsigned short* lA1 = &As[(wave * 32 + 16) * 32];
    unsigned short* lB0 = &Bs[(wave * 32) * 32];
    unsigned short* lB1 = &Bs[(wave * 32 + 16) * 32];

    const int fr = lane & 15;
    const int fk = (lane >> 4) * 8;
    const int wr = wave >> 1, wc = wave & 1;

    floatx4 acc[4][4];
#pragma unroll
    for (int i = 0; i < 4; i++)
#pragma unroll
        for (int j = 0; j < 4; j++) acc[i][j] = (floatx4){0.f, 0.f, 0.f, 0.f};

    for (int k0 = 0; k0 < K_; k0 += 32) {
        __syncthreads();                 // prior tile's ds_reads complete
        async16(ag0 + k0, lA0);
        async16(ag1 + k0, lA1);
        async16(bg0 + k0, lB0);
        async16(bg1 + k0, lB1);
        __syncthreads();                 // drains vmcnt -> LDS visible

        bf16x8 af[4], bfr[4];
#pragma unroll
        for (int i = 0; i < 4; i++)
            af[i] = *(const bf16x8*)&As[(wr * 64 + i * 16 + fr) * 32 + fk];
#pragma unroll
        for (int j = 0; j < 4; j++)
            bfr[j] = *(const bf16x8*)&Bs[(wc * 64 + j * 16 + fr) * 32 + fk];
#pragma unroll
        for (int i = 0; i < 4; i++)
#pragma unroll
            for (int j = 0; j < 4; j++)
                acc[i][j] = __builtin_amdgcn_mfma_f32_16x16x32_bf16(
                    af[i], bfr[j], acc[i][j], 0, 0, 0);
    }

    // epilogue
    const int rbase = (lane >> 4) * 4;
    if (p == 2) {    // V transposed: [B,H,HS,T]; rows (t) consecutive per reg
#pragma unroll
        for (int j = 0; j < 4; j++) {
            const int col = n0 + wc * 64 + j * 16 + fr;
            const float bz = bias[col];
            const int h = col >> 6, d = col & 63;
#pragma unroll
            for (int i = 0; i < 4; i++) {
                const int row0 = m0 + wr * 64 + i * 16 + rbase;
                const int bb = row0 >> 11, tt = row0 & 2047;
                ushort4 st;
                st.x = f2bf(acc[i][j][0] + bz);
                st.y = f2bf(acc[i][j][1] + bz);
                st.z = f2bf(acc[i][j][2] + bz);
                st.w = f2bf(acc[i][j][3] + bz);
                *(ushort4*)&vb[((size_t)(bb * H_ + h) * HS_ + d) * T_ + tt] = st;
            }
        }
    } else {
        unsigned short* out = (p == 0) ? qb : kb;
#pragma unroll
        for (int j = 0; j < 4; j++) {
            const int col = n0 + wc * 64 + j * 16 + fr;
            const float bz = bias[col];
            const int h = col >> 6, d = col & 63;
#pragma unroll
            for (int i = 0; i < 4; i++) {
#pragma unroll
                for (int pr = 0; pr < 4; pr++) {
                    const int row = m0 + wr * 64 + i * 16 + rbase + pr;
                    const int bb = row >> 11, tt = row & 2047;
                    out[((size_t)(bb * H_ + h) * T_ + tt) * HS_ + d] =
                        f2bf(acc[i][j][pr] + bz);
                }
            }
        }
    }
}

// ---------------------------------------------------------------------------
// Kernel 2: RoPE in-place on bf16 q/k [B,H,T,HS]. q also scaled by 1/8.
// ---------------------------------------------------------------------------
__global__ __launch_bounds__(256) void rope_kernel(unsigned short* __restrict__ qb,
                                                   unsigned short* __restrict__ kb)
{
    const int idx = blockIdx.x * 256 + threadIdx.x;
    const int d  = idx & 31;
    const int t  = (idx >> 5) & (T_ - 1);
    const int bh = idx >> 16;            // T_*32 == 65536
    const size_t base = ((size_t)bh * T_ + t) * HS_;

    const float inv_freq = powf(10000.0f, -(float)d * (1.0f / 32.0f));
    float s, c;
    sincosf((float)t * inv_freq, &s, &c);

    {   // q: rotate + fold in softmax scale 0.125
        float x1 = bf2f(qb[base + d]), x2 = bf2f(qb[base + d + 32]);
        qb[base + d]      = f2bf((x1 * c - x2 * s) * 0.125f);
        qb[base + d + 32] = f2bf((x2 * c + x1 * s) * 0.125f);
    }
    {
        float x1 = bf2f(kb[base + d]), x2 = bf2f(kb[base + d + 32]);
        kb[base + d]      = f2bf(x1 * c - x2 * s);
        kb[base + d + 32] = f2bf(x2 * c + x1 * s);
    }
}

// ---------------------------------------------------------------------------
// Kernel 3: MFMA flash attention (unchanged from round 5).
// ---------------------------------------------------------------------------
__global__ __launch_bounds__(256) void attn_kernel(
    const unsigned short* __restrict__ qb, const unsigned short* __restrict__ kb,
    const unsigned short* __restrict__ vt, unsigned short* __restrict__ yb)
{
    __shared__ unsigned short Ks[64 * 64];      // [key][dim^sw]
    __shared__ unsigned short Vs[64 * 64];      // [dim][key^sw]  (V^T)
    __shared__ unsigned short Ps[4][16 * 64];   // per-wave [qrow][key^sw]

    const int bh = blockIdx.x;
    const int b = bh >> 4, h = bh & 15;
    const int qt = blockIdx.y;
    const int r0 = qt * 64;
    const int tid  = threadIdx.x;
    const int lane = tid & 63;
    const int wave = tid >> 6;
    const int l4   = lane & 15;
    const int quad = lane >> 4;

    const int qrow_g = r0 + wave * 16 + l4;

    bf16x8 qf[2];
    {
        const unsigned short* qp = qb + ((size_t)bh * T_ + qrow_g) * HS_ + quad * 8;
        qf[0] = *(const bf16x8*)(qp);
        qf[1] = *(const bf16x8*)(qp + 32);
    }

    floatx4 o[4];
#pragma unroll
    for (int g = 0; g < 4; g++) o[g] = (floatx4){0.f, 0.f, 0.f, 0.f};
    float m = -1e30f, l = 0.f;

    const int srow = tid >> 2;
    const int sc16 = (tid & 3) * 16;
    const int ssw  = (srow & 7) * 8;
    const int psw  = (l4 & 7) * 8;

    for (int kt = 0; kt <= qt; kt++) {
        const unsigned short* kp = kb + ((size_t)bh * T_ + kt * 64 + srow) * HS_ + sc16;
        const uint4 k0 = *(const uint4*)kp;
        const uint4 k1 = *(const uint4*)(kp + 8);
        const unsigned short* vp = vt + ((size_t)(bh * 64 + srow)) * T_ + kt * 64 + sc16;
        const uint4 v0 = *(const uint4*)vp;
        const uint4 v1 = *(const uint4*)(vp + 8);

        __syncthreads();
        *(uint4*)&Ks[srow * 64 + ( sc16      ^ ssw)] = k0;
        *(uint4*)&Ks[srow * 64 + ((sc16 + 8) ^ ssw)] = k1;
        *(uint4*)&Vs[srow * 64 + ( sc16      ^ ssw)] = v0;
        *(uint4*)&Vs[srow * 64 + ((sc16 + 8) ^ ssw)] = v1;
        __syncthreads();

        floatx4 sf[4];
#pragma unroll
        for (int mg = 0; mg < 4; mg++) {
            const int key = mg * 16 + l4;
            const int ksw = (key & 7) * 8;
            const bf16x8 a0 = *(const bf16x8*)&Ks[key * 64 + ( (quad * 8)       ^ ksw)];
            const bf16x8 a1 = *(const bf16x8*)&Ks[key * 64 + (((quad * 8) + 32) ^ ksw)];
            floatx4 z = (floatx4){0.f, 0.f, 0.f, 0.f};
            z = __builtin_amdgcn_mfma_f32_16x16x32_bf16(a0, qf[0], z, 0, 0, 0);
            z = __builtin_amdgcn_mfma_f32_16x16x32_bf16(a1, qf[1], z, 0, 0, 0);
            sf[mg] = z;
        }

        if (kt == qt) {
#pragma unroll
            for (int mg = 0; mg < 4; mg++)
#pragma unroll
                for (int r = 0; r < 4; r++)
                    if (kt * 64 + 16 * mg + quad * 4 + r > qrow_g)
                        sf[mg][r] = -1e30f;
        }

        float tm = sf[0][0];
#pragma unroll
        for (int mg = 0; mg < 4; mg++)
#pragma unroll
            for (int r = 0; r < 4; r++) tm = fmaxf(tm, sf[mg][r]);
        tm = fmaxf(tm, __shfl_xor(tm, 16));
        tm = fmaxf(tm, __shfl_xor(tm, 32));
        const float mnew  = fmaxf(m, tm);
        const float alpha = __expf(m - mnew);

        float p[4][4];
        float ps = 0.f;
#pragma unroll
        for (int mg = 0; mg < 4; mg++)
#pragma unroll
            for (int r = 0; r < 4; r++) {
                p[mg][r] = __expf(sf[mg][r] - mnew);
                ps += p[mg][r];
            }
        ps += __shfl_xor(ps, 16);
        ps += __shfl_xor(ps, 32);
        l = l * alpha + ps;
        m = mnew;
#pragma unroll
        for (int g = 0; g < 4; g++) {
            o[g][0] *= alpha; o[g][1] *= alpha;
            o[g][2] *= alpha; o[g][3] *= alpha;
        }

#pragma unroll
        for (int mg = 0; mg < 4; mg++) {
            const int kb4 = 16 * mg + quad * 4;
            const int off = ((kb4 & ~7) ^ psw) | (kb4 & 7);
            uint2 w;
            w.x = pack2(p[mg][0], p[mg][1]);
            w.y = pack2(p[mg][2], p[mg][3]);
            *(uint2*)&Ps[wave][l4 * 64 + off] = w;
        }

        const bf16x8 pf0 = *(const bf16x8*)&Ps[wave][l4 * 64 + ( (quad * 8)       ^ psw)];
        const bf16x8 pf1 = *(const bf16x8*)&Ps[wave][l4 * 64 + (((quad * 8) + 32) ^ psw)];
#pragma unroll
        for (int g = 0; g < 4; g++) {
            const int vd  = g * 16 + l4;
            const int vsw = (vd & 7) * 8;
            const bf16x8 va0 = *(const bf16x8*)&Vs[vd * 64 + ( (quad * 8)       ^ vsw)];
            const bf16x8 va1 = *(const bf16x8*)&Vs[vd * 64 + (((quad * 8) + 32) ^ vsw)];
            o[g] = __builtin_amdgcn_mfma_f32_16x16x32_bf16(va0, pf0, o[g], 0, 0, 0);
            o[g] = __builtin_amdgcn_mfma_f32_16x16x32_bf16(va1, pf1, o[g], 0, 0, 0);
        }
    }

    const float invl = 1.f / l;
    unsigned short* yrow = yb + ((size_t)(b * T_ + qrow_g) * H_ + h) * HS_;
#pragma unroll
    for (int g = 0; g < 4; g++) {
        ushort4 st;
        st.x = f2bf(o[g][0] * invl);
        st.y = f2bf(o[g][1] * invl);
        st.z = f2bf(o[g][2] * invl);
        st.w = f2bf(o[g][3] * invl);
        *(ushort4*)&yrow[16 * g + quad * 4] = st;
    }
}

// ---------------------------------------------------------------------------
// Kernel 4: output projection (m97-style). A = yb bf16, B = wcT bf16 [n][k].
// out fp32 [4096][1024]. grid (8, 32), block 256.
// ---------------------------------------------------------------------------
__global__ __launch_bounds__(256) void out_gemm(
    const unsigned short* __restrict__ A, const unsigned short* __restrict__ wcT,
    const float* __restrict__ bias, float* __restrict__ out)
{
    __shared__ unsigned short As[128 * 32];
    __shared__ unsigned short Bs[128 * 32];

    const int tid  = threadIdx.x;
    const int lane = tid & 63;
    const int wave = tid >> 6;
    const int n0 = blockIdx.x * 128;
    const int m0 = blockIdx.y * 128;

    const int lrow = lane >> 2, lch = (lane & 3) * 8;
    const unsigned short* ag0 = A + (size_t)(m0 + wave * 32 + lrow) * K_ + lch;
    const unsigned short* ag1 = ag0 + (size_t)16 * K_;
    const unsigned short* bg0 = wcT + (size_t)(n0 + wave * 32 + lrow) * K_ + lch;
    const unsigned short* bg1 = bg0 + (size_t)16 * K_;
    unsigned short* lA0 = &As[(wave * 32) * 32];
    unsigned short* lA1 = &As[(wave * 32 + 16) * 32];
    unsigned short* lB0 = &Bs[(wave * 32) * 32];
    unsigned short* lB1 = &Bs[(wave * 32 + 16) * 32];

    const int fr = lane & 15;
    const int fk = (lane >> 4) * 8;
    const int wr = wave >> 1, wc = wave & 1;

    floatx4 acc[4][4];
#pragma unroll
    for (int i = 0; i < 4; i++)
#pragma unroll
        for (int j = 0; j < 4; j++) acc[i][j] = (floatx4){0.f, 0.f, 0.f, 0.f};

    for (int k0 = 0; k0 < K_; k0 += 32) {
        __syncthreads();
        async16(ag0 + k0, lA0);
        async16(ag1 + k0, lA1);
        async16(bg0 + k0, lB0);
        async16(bg1 + k0, lB1);
        __syncthreads();

        bf16x8 af[4], bfr[4];
#pragma unroll
        for (int i = 0; i < 4; i++)
            af[i] = *(const bf16x8*)&As[(wr * 64 + i * 16 + fr) * 32 + fk];
#pragma unroll
        for (int j = 0; j < 4; j++)
            bfr[j] = *(const bf16x8*)&Bs[(wc * 64 + j * 16 + fr) * 32 + fk];
#pragma unroll
        for (int i = 0; i < 4; i++)
#pragma unroll
            for (int j = 0; j < 4; j++)
                acc[i][j] = __builtin_amdgcn_mfma_f32_16x16x32_bf16(
                    af[i], bfr[j], acc[i][j], 0, 0, 0);
    }

    const int rbase = (lane >> 4) * 4;
#pragma unroll
    for (int j = 0; j < 4; j++) {
        const int col = n0 + wc * 64 + j * 16 + fr;
        const float bz = bias[col];
#pragma unroll
        for (int i = 0; i < 4; i++) {
#pragma unroll
            for (int pr = 0; pr < 4; pr++) {
                const int row = m0 + wr * 64 + i * 16 + rbase + pr;
                out[(size_t)row * N_ + col] = acc[i][j][pr] + bz;
            }
        }
    }
}

// ---------------------------------------------------------------------------
extern "C" void kernel_launch(void* const* d_in, const int* in_sizes, int n_in,
                              void* d_out, int out_size, void* d_ws, size_t ws_size,
                              hipStream_t stream) {
    const float* x  = (const float*)d_in[0];
    const float* wq = (const float*)d_in[1];
    const float* bq = (const float*)d_in[2];
    const float* wk = (const float*)d_in[3];
    const float* bk = (const float*)d_in[4];
    const float* wv = (const float*)d_in[5];
    const float* bv = (const float*)d_in[6];
    const float* wc = (const float*)d_in[7];
    const float* bc = (const float*)d_in[8];
    float* out = (float*)d_out;

    // ws (ushort units): qb 0, kb 4M, vb 8M, yb 12M, xb 16M, wT 20M..24M (48 MB)
    unsigned short* ws  = (unsigned short*)d_ws;
    unsigned short* qb  = ws;                        // [B,H,T,HS]
    unsigned short* kb  = ws + (size_t)4194304;      // [B,H,T,HS]
    unsigned short* vb  = ws + (size_t)8388608;      // [B,H,HS,T] (V^T)
    unsigned short* yb  = ws + (size_t)12582912;     // [B,T,C]
    unsigned short* xb  = ws + (size_t)16777216;     // x bf16
    unsigned short* wT  = ws + (size_t)20971520;     // 4x bf16 [n][k] (wq,wk,wv,wc)
    unsigned short* wcT = wT + ((size_t)3 << 20);

    convert_x<<<4096, 256, 0, stream>>>(x, xb);
    transpose_w<<<dim3(16, 16, 4), 256, 0, stream>>>(wq, wk, wv, wc, wT);
    qkv_gemm<<<dim3(24, 32), 256, 0, stream>>>(xb, wT, bq, bk, bv, qb, kb, vb);
    rope_kernel<<<(B_ * H_ * T_ * 32) / 256, 256, 0, stream>>>(qb, kb);
    attn_kernel<<<dim3(32, 32), 256, 0, stream>>>(qb, kb, vb, yb);
    out_gemm<<<dim3(8, 32), 256, 0, stream>>>(yb, wcT, bc, out);
}

// Round 7
// 215.293 us; speedup vs baseline: 11.8666x; 1.0743x over previous
//
#include <hip/hip_runtime.h>

#define B_  2
#define T_  2048
#define C_  1024
#define H_  16
#define HS_ 64
#define M_  4096
#define N_  1024
#define K_  1024

typedef float floatx4 __attribute__((ext_vector_type(4)));
typedef short bf16x8  __attribute__((ext_vector_type(8)));

__device__ __forceinline__ float bf2f(unsigned short u) {
    return __uint_as_float(((unsigned int)u) << 16);
}
__device__ __forceinline__ unsigned short f2bf(float f) {
    unsigned int u = __float_as_uint(f);
    return (unsigned short)((u + 0x7fffu + ((u >> 16) & 1u)) >> 16);
}
__device__ __forceinline__ unsigned int pack2(float a, float b) {
    return (unsigned int)f2bf(a) | ((unsigned int)f2bf(b) << 16);
}
// async global->LDS, 16B per lane; lds dest = wave-uniform base + lane*16
__device__ __forceinline__ void async16(const unsigned short* g, unsigned short* l) {
    __builtin_amdgcn_global_load_lds(
        (const __attribute__((address_space(1))) unsigned int*)g,
        (__attribute__((address_space(3))) unsigned int*)l, 16, 0, 0);
}

// ---------------------------------------------------------------------------
// Prep 1: x fp32 -> bf16 [4096][1024]. grid 4096, block 256, 4 elems/thread.
// ---------------------------------------------------------------------------
__global__ __launch_bounds__(256) void convert_x(const float* __restrict__ x,
                                                 unsigned short* __restrict__ xb)
{
    const size_t i = ((size_t)blockIdx.x * 256 + threadIdx.x) * 4;
    const float4 v = *(const float4*)(x + i);
    ushort4 st;
    st.x = f2bf(v.x); st.y = f2bf(v.y); st.z = f2bf(v.z); st.w = f2bf(v.w);
    *(ushort4*)(xb + i) = st;
}

// ---------------------------------------------------------------------------
// Prep 2: transpose+convert weights: w fp32 [K][N] -> wT bf16 [N][K].
// grid (16,16,4): 64x64 tiles, z selects {wq,wk,wv,wc}. block 256.
// ---------------------------------------------------------------------------
__global__ __launch_bounds__(256) void transpose_w(
    const float* __restrict__ w0, const float* __restrict__ w1,
    const float* __restrict__ w2, const float* __restrict__ w3,
    unsigned short* __restrict__ wTall)
{
    __shared__ float tile[64][65];
    const int z = blockIdx.z;
    const float* w = (z == 0) ? w0 : (z == 1) ? w1 : (z == 2) ? w2 : w3;
    unsigned short* wT = wTall + ((size_t)z << 20);

    const int n0 = blockIdx.x * 64, k0 = blockIdx.y * 64;
    const int t = threadIdx.x;
    const int r = t >> 2, cq = (t & 3) * 16;

    const float4* src = (const float4*)(w + (size_t)(k0 + r) * N_ + n0 + cq);
    const float4 v0 = src[0], v1 = src[1], v2 = src[2], v3 = src[3];
    tile[r][cq+0]=v0.x; tile[r][cq+1]=v0.y; tile[r][cq+2]=v0.z; tile[r][cq+3]=v0.w;
    tile[r][cq+4]=v1.x; tile[r][cq+5]=v1.y; tile[r][cq+6]=v1.z; tile[r][cq+7]=v1.w;
    tile[r][cq+8]=v2.x; tile[r][cq+9]=v2.y; tile[r][cq+10]=v2.z; tile[r][cq+11]=v2.w;
    tile[r][cq+12]=v3.x; tile[r][cq+13]=v3.y; tile[r][cq+14]=v3.z; tile[r][cq+15]=v3.w;
    __syncthreads();

    const int rn = t >> 2, ck = (t & 3) * 16;
    unsigned int o[8];
#pragma unroll
    for (int ii = 0; ii < 8; ii++)
        o[ii] = pack2(tile[ck + 2*ii][rn], tile[ck + 2*ii + 1][rn]);
    unsigned short* dst = wT + (size_t)(n0 + rn) * K_ + k0 + ck;
    *(uint4*)dst       = make_uint4(o[0], o[1], o[2], o[3]);
    *(uint4*)(dst + 8) = make_uint4(o[4], o[5], o[6], o[7]);
}

// ---------------------------------------------------------------------------
// Kernel 1: fused QKV GEMM + RoPE epilogue. A = xb bf16, B = wT bf16 [n][k].
// q (scaled by 0.125*log2e), k -> [B,H,T,HS] with RoPE applied;
// v -> transposed [B,H,HS,T]. grid (24, 32), block 256.
// ---------------------------------------------------------------------------
__global__ __launch_bounds__(256) void qkv_gemm(
    const unsigned short* __restrict__ xb, const unsigned short* __restrict__ wT,
    const float* __restrict__ bq, const float* __restrict__ bk,
    const float* __restrict__ bv,
    unsigned short* __restrict__ qb, unsigned short* __restrict__ kb,
    unsigned short* __restrict__ vb)
{
    __shared__ unsigned short As[128 * 32];   // [m][k], contiguous (async layout)
    __shared__ unsigned short Bs[128 * 32];   // [n][k]

    const int tid  = threadIdx.x;
    const int lane = tid & 63;
    const int wave = tid >> 6;
    const int p  = blockIdx.x >> 3;
    const int n0 = (blockIdx.x & 7) * 128;
    const int m0 = blockIdx.y * 128;
    const float* bias = (p == 0) ? bq : (p == 1) ? bk : bv;

    const int lrow = lane >> 2, lch = (lane & 3) * 8;
    const unsigned short* ag0 = xb + (size_t)(m0 + wave * 32 + lrow) * K_ + lch;
    const unsigned short* ag1 = ag0 + (size_t)16 * K_;
    const unsigned short* wb  = wT + ((size_t)p << 20);
    const unsigned short* bg0 = wb + (size_t)(n0 + wave * 32 + lrow) * K_ + lch;
    const unsigned short* bg1 = bg0 + (size_t)16 * K_;
    unsigned short* lA0 = &As[(wave * 32) * 32];
    unsigned short* lA1 = &As[(wave * 32 + 16) * 32];
    unsigned short* lB0 = &Bs[(wave * 32) * 32];
    unsigned short* lB1 = &Bs[(wave * 32 + 16) * 32];

    const int fr = lane & 15;
    const int fk = (lane >> 4) * 8;
    const int wr = wave >> 1, wc = wave & 1;

    floatx4 acc[4][4];
#pragma unroll
    for (int i = 0; i < 4; i++)
#pragma unroll
        for (int j = 0; j < 4; j++) acc[i][j] = (floatx4){0.f, 0.f, 0.f, 0.f};

    for (int k0 = 0; k0 < K_; k0 += 32) {
        __syncthreads();
        async16(ag0 + k0, lA0);
        async16(ag1 + k0, lA1);
        async16(bg0 + k0, lB0);
        async16(bg1 + k0, lB1);
        __syncthreads();

        bf16x8 af[4], bfr[4];
#pragma unroll
        for (int i = 0; i < 4; i++)
            af[i] = *(const bf16x8*)&As[(wr * 64 + i * 16 + fr) * 32 + fk];
#pragma unroll
        for (int j = 0; j < 4; j++)
            bfr[j] = *(const bf16x8*)&Bs[(wc * 64 + j * 16 + fr) * 32 + fk];
#pragma unroll
        for (int i = 0; i < 4; i++)
#pragma unroll
            for (int j = 0; j < 4; j++)
                acc[i][j] = __builtin_amdgcn_mfma_f32_16x16x32_bf16(
                    af[i], bfr[j], acc[i][j], 0, 0, 0);
    }

    const int rbase = (lane >> 4) * 4;
    const int h = (n0 + wc * 64) >> 6;          // all 4 cols of a lane share head
    if (p == 2) {    // V transposed: [B,H,HS,T]
#pragma unroll
        for (int j = 0; j < 4; j++) {
            const int col = n0 + wc * 64 + j * 16 + fr;
            const float bz = bias[col];
            const int d = col & 63;
#pragma unroll
            for (int i = 0; i < 4; i++) {
                const int row0 = m0 + wr * 64 + i * 16 + rbase;
                const int bb = row0 >> 11, tt = row0 & 2047;
                ushort4 st;
                st.x = f2bf(acc[i][j][0] + bz);
                st.y = f2bf(acc[i][j][1] + bz);
                st.z = f2bf(acc[i][j][2] + bz);
                st.w = f2bf(acc[i][j][3] + bz);
                *(ushort4*)&vb[((size_t)(bb * H_ + h) * HS_ + d) * T_ + tt] = st;
            }
        }
    } else {
        // q/k with fused RoPE. Lane's 4 cols = d, d+16, d+32, d+48 (d = fr):
        // rotation pairs (j0,j2) and (j1,j3).
        unsigned short* out = (p == 0) ? qb : kb;
        // q folds softmax scale 1/8 and log2(e) so attention uses exp2 directly
        const float qsc = (p == 0) ? 0.18033688011111772f : 1.0f;
        const float bz0 = bias[n0 + wc * 64 + fr];
        const float bz1 = bias[n0 + wc * 64 + 16 + fr];
        const float bz2 = bias[n0 + wc * 64 + 32 + fr];
        const float bz3 = bias[n0 + wc * 64 + 48 + fr];
        // inv_freq[d] = 10000^(-d/32) = 2^(-d*log2(1e4)/32)
        const float nl = -0.41524101186279297f;   // -log2(10000)/32
        const float if0 = exp2f((float)fr * nl);
        const float if1 = exp2f((float)(fr + 16) * nl);
#pragma unroll
        for (int i = 0; i < 4; i++) {
#pragma unroll
            for (int pr = 0; pr < 4; pr++) {
                const int row = m0 + wr * 64 + i * 16 + rbase + pr;
                const int bb = row >> 11, tt = row & 2047;
                float s0, c0, s1, c1;
                __sincosf((float)tt * if0, &s0, &c0);
                __sincosf((float)tt * if1, &s1, &c1);
                const float v0 = acc[i][0][pr] + bz0;
                const float v1 = acc[i][1][pr] + bz1;
                const float v2 = acc[i][2][pr] + bz2;
                const float v3 = acc[i][3][pr] + bz3;
                unsigned short* ob = out + ((size_t)(bb * H_ + h) * T_ + tt) * HS_ + fr;
                ob[0]  = f2bf((v0 * c0 - v2 * s0) * qsc);
                ob[16] = f2bf((v1 * c1 - v3 * s1) * qsc);
                ob[32] = f2bf((v2 * c0 + v0 * s0) * qsc);
                ob[48] = f2bf((v3 * c1 + v1 * s1) * qsc);
            }
        }
    }
}

// ---------------------------------------------------------------------------
// Kernel 3: MFMA flash attention, double-buffered K/V tiles + reg prefetch.
// qt reversed (big blocks first). Softmax in exp2 domain (scale folded in q).
// grid = (32, 32), block 256.
// ---------------------------------------------------------------------------
__global__ __launch_bounds__(256) void attn_kernel(
    const unsigned short* __restrict__ qb, const unsigned short* __restrict__ kb,
    const unsigned short* __restrict__ vt, unsigned short* __restrict__ yb)
{
    __shared__ unsigned short Ks[2][64 * 64];   // [buf][key][dim^sw]
    __shared__ unsigned short Vs[2][64 * 64];   // [buf][dim][key^sw]
    __shared__ unsigned short Ps[4][16 * 64];   // per-wave [qrow][key^sw]

    const int bh = blockIdx.x;
    const int b = bh >> 4, h = bh & 15;
    const int qt = (int)gridDim.y - 1 - blockIdx.y;   // LPT: big blocks first
    const int r0 = qt * 64;
    const int tid  = threadIdx.x;
    const int lane = tid & 63;
    const int wave = tid >> 6;
    const int l4   = lane & 15;
    const int quad = lane >> 4;

    const int qrow_g = r0 + wave * 16 + l4;

    bf16x8 qf[2];
    {
        const unsigned short* qp = qb + ((size_t)bh * T_ + qrow_g) * HS_ + quad * 8;
        qf[0] = *(const bf16x8*)(qp);
        qf[1] = *(const bf16x8*)(qp + 32);
    }

    floatx4 o[4];
#pragma unroll
    for (int g = 0; g < 4; g++) o[g] = (floatx4){0.f, 0.f, 0.f, 0.f};
    float m = -1e30f, l = 0.f;

    const int srow = tid >> 2;
    const int sc16 = (tid & 3) * 16;
    const int ssw  = (srow & 7) * 8;
    const int psw  = (l4 & 7) * 8;

    const unsigned short* kp = kb + ((size_t)bh * T_ + srow) * HS_ + sc16;
    const unsigned short* vp = vt + ((size_t)(bh * 64 + srow)) * T_ + sc16;

    // stage tile 0 into buffer 0
    uint4 rk0 = *(const uint4*)kp;
    uint4 rk1 = *(const uint4*)(kp + 8);
    uint4 rv0 = *(const uint4*)vp;
    uint4 rv1 = *(const uint4*)(vp + 8);
    *(uint4*)&Ks[0][srow * 64 + ( sc16      ^ ssw)] = rk0;
    *(uint4*)&Ks[0][srow * 64 + ((sc16 + 8) ^ ssw)] = rk1;
    *(uint4*)&Vs[0][srow * 64 + ( sc16      ^ ssw)] = rv0;
    *(uint4*)&Vs[0][srow * 64 + ((sc16 + 8) ^ ssw)] = rv1;

    for (int kt = 0; kt <= qt; kt++) {
        const int cur = kt & 1;
        if (kt < qt) {   // prefetch next tile into regs (latency hides under compute)
            const unsigned short* kpn = kp + (size_t)(kt + 1) * (64 * HS_);
            const unsigned short* vpn = vp + (kt + 1) * 64;
            rk0 = *(const uint4*)kpn;
            rk1 = *(const uint4*)(kpn + 8);
            rv0 = *(const uint4*)vpn;
            rv1 = *(const uint4*)(vpn + 8);
        }
        __syncthreads();   // buf[cur] visible; all waves done with buf[cur^1]

        floatx4 sf[4];
#pragma unroll
        for (int mg = 0; mg < 4; mg++) {
            const int key = mg * 16 + l4;
            const int ksw = (key & 7) * 8;
            const bf16x8 a0 = *(const bf16x8*)&Ks[cur][key * 64 + ( (quad * 8)       ^ ksw)];
            const bf16x8 a1 = *(const bf16x8*)&Ks[cur][key * 64 + (((quad * 8) + 32) ^ ksw)];
            floatx4 z = (floatx4){0.f, 0.f, 0.f, 0.f};
            z = __builtin_amdgcn_mfma_f32_16x16x32_bf16(a0, qf[0], z, 0, 0, 0);
            z = __builtin_amdgcn_mfma_f32_16x16x32_bf16(a1, qf[1], z, 0, 0, 0);
            sf[mg] = z;
        }

        if (kt == qt) {   // causal mask on diagonal tile
#pragma unroll
            for (int mg = 0; mg < 4; mg++)
#pragma unroll
                for (int r = 0; r < 4; r++)
                    if (kt * 64 + 16 * mg + quad * 4 + r > qrow_g)
                        sf[mg][r] = -1e30f;
        }

        float tm = sf[0][0];
#pragma unroll
        for (int mg = 0; mg < 4; mg++)
#pragma unroll
            for (int r = 0; r < 4; r++) tm = fmaxf(tm, sf[mg][r]);
        tm = fmaxf(tm, __shfl_xor(tm, 16));
        tm = fmaxf(tm, __shfl_xor(tm, 32));
        const float mnew  = fmaxf(m, tm);
        const float alpha = exp2f(m - mnew);

        float p[4][4];
        float ps = 0.f;
#pragma unroll
        for (int mg = 0; mg < 4; mg++)
#pragma unroll
            for (int r = 0; r < 4; r++) {
                p[mg][r] = exp2f(sf[mg][r] - mnew);
                ps += p[mg][r];
            }
        ps += __shfl_xor(ps, 16);
        ps += __shfl_xor(ps, 32);
        l = l * alpha + ps;
        m = mnew;
#pragma unroll
        for (int g = 0; g < 4; g++) {
            o[g][0] *= alpha; o[g][1] *= alpha;
            o[g][2] *= alpha; o[g][3] *= alpha;
        }

#pragma unroll
        for (int mg = 0; mg < 4; mg++) {
            const int kb4 = 16 * mg + quad * 4;
            const int off = ((kb4 & ~7) ^ psw) | (kb4 & 7);
            uint2 w;
            w.x = pack2(p[mg][0], p[mg][1]);
            w.y = pack2(p[mg][2], p[mg][3]);
            *(uint2*)&Ps[wave][l4 * 64 + off] = w;
        }

        const bf16x8 pf0 = *(const bf16x8*)&Ps[wave][l4 * 64 + ( (quad * 8)       ^ psw)];
        const bf16x8 pf1 = *(const bf16x8*)&Ps[wave][l4 * 64 + (((quad * 8) + 32) ^ psw)];
#pragma unroll
        for (int g = 0; g < 4; g++) {
            const int vd  = g * 16 + l4;
            const int vsw = (vd & 7) * 8;
            const bf16x8 va0 = *(const bf16x8*)&Vs[cur][vd * 64 + ( (quad * 8)       ^ vsw)];
            const bf16x8 va1 = *(const bf16x8*)&Vs[cur][vd * 64 + (((quad * 8) + 32) ^ vsw)];
            o[g] = __builtin_amdgcn_mfma_f32_16x16x32_bf16(va0, pf0, o[g], 0, 0, 0);
            o[g] = __builtin_amdgcn_mfma_f32_16x16x32_bf16(va1, pf1, o[g], 0, 0, 0);
        }

        if (kt < qt) {   // stage next tile (other buffer); no barrier needed here
            const int nxt = cur ^ 1;
            *(uint4*)&Ks[nxt][srow * 64 + ( sc16      ^ ssw)] = rk0;
            *(uint4*)&Ks[nxt][srow * 64 + ((sc16 + 8) ^ ssw)] = rk1;
            *(uint4*)&Vs[nxt][srow * 64 + ( sc16      ^ ssw)] = rv0;
            *(uint4*)&Vs[nxt][srow * 64 + ((sc16 + 8) ^ ssw)] = rv1;
        }
    }

    const float invl = 1.f / l;
    unsigned short* yrow = yb + ((size_t)(b * T_ + qrow_g) * H_ + h) * HS_;
#pragma unroll
    for (int g = 0; g < 4; g++) {
        ushort4 st;
        st.x = f2bf(o[g][0] * invl);
        st.y = f2bf(o[g][1] * invl);
        st.z = f2bf(o[g][2] * invl);
        st.w = f2bf(o[g][3] * invl);
        *(ushort4*)&yrow[16 * g + quad * 4] = st;
    }
}

// ---------------------------------------------------------------------------
// Kernel 4: output projection (m97-style). A = yb bf16, B = wcT bf16 [n][k].
// out fp32 [4096][1024]. grid (8, 32), block 256.
// ---------------------------------------------------------------------------
__global__ __launch_bounds__(256) void out_gemm(
    const unsigned short* __restrict__ A, const unsigned short* __restrict__ wcT,
    const float* __restrict__ bias, float* __restrict__ out)
{
    __shared__ unsigned short As[128 * 32];
    __shared__ unsigned short Bs[128 * 32];

    const int tid  = threadIdx.x;
    const int lane = tid & 63;
    const int wave = tid >> 6;
    const int n0 = blockIdx.x * 128;
    const int m0 = blockIdx.y * 128;

    const int lrow = lane >> 2, lch = (lane & 3) * 8;
    const unsigned short* ag0 = A + (size_t)(m0 + wave * 32 + lrow) * K_ + lch;
    const unsigned short* ag1 = ag0 + (size_t)16 * K_;
    const unsigned short* bg0 = wcT + (size_t)(n0 + wave * 32 + lrow) * K_ + lch;
    const unsigned short* bg1 = bg0 + (size_t)16 * K_;
    unsigned short* lA0 = &As[(wave * 32) * 32];
    unsigned short* lA1 = &As[(wave * 32 + 16) * 32];
    unsigned short* lB0 = &Bs[(wave * 32) * 32];
    unsigned short* lB1 = &Bs[(wave * 32 + 16) * 32];

    const int fr = lane & 15;
    const int fk = (lane >> 4) * 8;
    const int wr = wave >> 1, wc = wave & 1;

    floatx4 acc[4][4];
#pragma unroll
    for (int i = 0; i < 4; i++)
#pragma unroll
        for (int j = 0; j < 4; j++) acc[i][j] = (floatx4){0.f, 0.f, 0.f, 0.f};

    for (int k0 = 0; k0 < K_; k0 += 32) {
        __syncthreads();
        async16(ag0 + k0, lA0);
        async16(ag1 + k0, lA1);
        async16(bg0 + k0, lB0);
        async16(bg1 + k0, lB1);
        __syncthreads();

        bf16x8 af[4], bfr[4];
#pragma unroll
        for (int i = 0; i < 4; i++)
            af[i] = *(const bf16x8*)&As[(wr * 64 + i * 16 + fr) * 32 + fk];
#pragma unroll
        for (int j = 0; j < 4; j++)
            bfr[j] = *(const bf16x8*)&Bs[(wc * 64 + j * 16 + fr) * 32 + fk];
#pragma unroll
        for (int i = 0; i < 4; i++)
#pragma unroll
            for (int j = 0; j < 4; j++)
                acc[i][j] = __builtin_amdgcn_mfma_f32_16x16x32_bf16(
                    af[i], bfr[j], acc[i][j], 0, 0, 0);
    }

    const int rbase = (lane >> 4) * 4;
#pragma unroll
    for (int j = 0; j < 4; j++) {
        const int col = n0 + wc * 64 + j * 16 + fr;
        const float bz = bias[col];
#pragma unroll
        for (int i = 0; i < 4; i++) {
#pragma unroll
            for (int pr = 0; pr < 4; pr++) {
                const int row = m0 + wr * 64 + i * 16 + rbase + pr;
                out[(size_t)row * N_ + col] = acc[i][j][pr] + bz;
            }
        }
    }
}

// ---------------------------------------------------------------------------
extern "C" void kernel_launch(void* const* d_in, const int* in_sizes, int n_in,
                              void* d_out, int out_size, void* d_ws, size_t ws_size,
                              hipStream_t stream) {
    const float* x  = (const float*)d_in[0];
    const float* wq = (const float*)d_in[1];
    const float* bq = (const float*)d_in[2];
    const float* wk = (const float*)d_in[3];
    const float* bk = (const float*)d_in[4];
    const float* wv = (const float*)d_in[5];
    const float* bv = (const float*)d_in[6];
    const float* wc = (const float*)d_in[7];
    const float* bc = (const float*)d_in[8];
    float* out = (float*)d_out;

    // ws (ushort units): qb 0, kb 4M, vb 8M, yb 12M, xb 16M, wT 20M..24M (48 MB)
    unsigned short* ws  = (unsigned short*)d_ws;
    unsigned short* qb  = ws;                        // [B,H,T,HS] (rope+scale applied)
    unsigned short* kb  = ws + (size_t)4194304;      // [B,H,T,HS] (rope applied)
    unsigned short* vb  = ws + (size_t)8388608;      // [B,H,HS,T] (V^T)
    unsigned short* yb  = ws + (size_t)12582912;     // [B,T,C]
    unsigned short* xb  = ws + (size_t)16777216;     // x bf16
    unsigned short* wT  = ws + (size_t)20971520;     // 4x bf16 [n][k] (wq,wk,wv,wc)
    unsigned short* wcT = wT + ((size_t)3 << 20);

    convert_x<<<4096, 256, 0, stream>>>(x, xb);
    transpose_w<<<dim3(16, 16, 4), 256, 0, stream>>>(wq, wk, wv, wc, wT);
    qkv_gemm<<<dim3(24, 32), 256, 0, stream>>>(xb, wT, bq, bk, bv, qb, kb, vb);
    attn_kernel<<<dim3(32, 32), 256, 0, stream>>>(qb, kb, vb, yb);
    out_gemm<<<dim3(8, 32), 256, 0, stream>>>(yb, wcT, bc, out);
}

// Round 8
// 211.130 us; speedup vs baseline: 12.1006x; 1.0197x over previous
//
#include <hip/hip_runtime.h>

#define B_  2
#define T_  2048
#define C_  1024
#define H_  16
#define HS_ 64
#define M_  4096
#define N_  1024
#define K_  1024

typedef float floatx4 __attribute__((ext_vector_type(4)));
typedef short bf16x8  __attribute__((ext_vector_type(8)));

__device__ __forceinline__ float bf2f(unsigned short u) {
    return __uint_as_float(((unsigned int)u) << 16);
}
__device__ __forceinline__ unsigned short f2bf(float f) {
    unsigned int u = __float_as_uint(f);
    return (unsigned short)((u + 0x7fffu + ((u >> 16) & 1u)) >> 16);
}
__device__ __forceinline__ unsigned int pack2(float a, float b) {
    return (unsigned int)f2bf(a) | ((unsigned int)f2bf(b) << 16);
}
// truncating bf16 pair pack: one v_perm_b32 (low16 = hi(a), high16 = hi(b))
__device__ __forceinline__ unsigned int pack2t(float a, float b) {
    return __builtin_amdgcn_perm(__float_as_uint(b), __float_as_uint(a), 0x07060302u);
}
// async global->LDS, 16B per lane; lds dest = wave-uniform base + lane*16
__device__ __forceinline__ void async16(const unsigned short* g, unsigned short* l) {
    __builtin_amdgcn_global_load_lds(
        (const __attribute__((address_space(1))) unsigned int*)g,
        (__attribute__((address_space(3))) unsigned int*)l, 16, 0, 0);
}

// ---------------------------------------------------------------------------
// Prep 1: x fp32 -> bf16 [4096][1024]. grid 4096, block 256.
// ---------------------------------------------------------------------------
__global__ __launch_bounds__(256) void convert_x(const float* __restrict__ x,
                                                 unsigned short* __restrict__ xb)
{
    const size_t i = ((size_t)blockIdx.x * 256 + threadIdx.x) * 4;
    const float4 v = *(const float4*)(x + i);
    ushort4 st;
    st.x = f2bf(v.x); st.y = f2bf(v.y); st.z = f2bf(v.z); st.w = f2bf(v.w);
    *(ushort4*)(xb + i) = st;
}

// ---------------------------------------------------------------------------
// Prep 2: transpose+convert weights: w fp32 [K][N] -> wT bf16 [N][K].
// grid (16,16,4): 64x64 tiles, z selects {wq,wk,wv,wc}. block 256.
// ---------------------------------------------------------------------------
__global__ __launch_bounds__(256) void transpose_w(
    const float* __restrict__ w0, const float* __restrict__ w1,
    const float* __restrict__ w2, const float* __restrict__ w3,
    unsigned short* __restrict__ wTall)
{
    __shared__ float tile[64][65];
    const int z = blockIdx.z;
    const float* w = (z == 0) ? w0 : (z == 1) ? w1 : (z == 2) ? w2 : w3;
    unsigned short* wT = wTall + ((size_t)z << 20);

    const int n0 = blockIdx.x * 64, k0 = blockIdx.y * 64;
    const int t = threadIdx.x;
    const int r = t >> 2, cq = (t & 3) * 16;

    const float4* src = (const float4*)(w + (size_t)(k0 + r) * N_ + n0 + cq);
    const float4 v0 = src[0], v1 = src[1], v2 = src[2], v3 = src[3];
    tile[r][cq+0]=v0.x; tile[r][cq+1]=v0.y; tile[r][cq+2]=v0.z; tile[r][cq+3]=v0.w;
    tile[r][cq+4]=v1.x; tile[r][cq+5]=v1.y; tile[r][cq+6]=v1.z; tile[r][cq+7]=v1.w;
    tile[r][cq+8]=v2.x; tile[r][cq+9]=v2.y; tile[r][cq+10]=v2.z; tile[r][cq+11]=v2.w;
    tile[r][cq+12]=v3.x; tile[r][cq+13]=v3.y; tile[r][cq+14]=v3.z; tile[r][cq+15]=v3.w;
    __syncthreads();

    const int rn = t >> 2, ck = (t & 3) * 16;
    unsigned int o[8];
#pragma unroll
    for (int ii = 0; ii < 8; ii++)
        o[ii] = pack2(tile[ck + 2*ii][rn], tile[ck + 2*ii + 1][rn]);
    unsigned short* dst = wT + (size_t)(n0 + rn) * K_ + k0 + ck;
    *(uint4*)dst       = make_uint4(o[0], o[1], o[2], o[3]);
    *(uint4*)(dst + 8) = make_uint4(o[4], o[5], o[6], o[7]);
}

// ---------------------------------------------------------------------------
// Kernel 1: fused QKV GEMM + RoPE epilogue (unchanged from round 7).
// grid (24, 32), block 256.
// ---------------------------------------------------------------------------
__global__ __launch_bounds__(256) void qkv_gemm(
    const unsigned short* __restrict__ xb, const unsigned short* __restrict__ wT,
    const float* __restrict__ bq, const float* __restrict__ bk,
    const float* __restrict__ bv,
    unsigned short* __restrict__ qb, unsigned short* __restrict__ kb,
    unsigned short* __restrict__ vb)
{
    __shared__ unsigned short As[128 * 32];
    __shared__ unsigned short Bs[128 * 32];

    const int tid  = threadIdx.x;
    const int lane = tid & 63;
    const int wave = tid >> 6;
    const int p  = blockIdx.x >> 3;
    const int n0 = (blockIdx.x & 7) * 128;
    const int m0 = blockIdx.y * 128;
    const float* bias = (p == 0) ? bq : (p == 1) ? bk : bv;

    const int lrow = lane >> 2, lch = (lane & 3) * 8;
    const unsigned short* ag0 = xb + (size_t)(m0 + wave * 32 + lrow) * K_ + lch;
    const unsigned short* ag1 = ag0 + (size_t)16 * K_;
    const unsigned short* wb  = wT + ((size_t)p << 20);
    const unsigned short* bg0 = wb + (size_t)(n0 + wave * 32 + lrow) * K_ + lch;
    const unsigned short* bg1 = bg0 + (size_t)16 * K_;
    unsigned short* lA0 = &As[(wave * 32) * 32];
    unsigned short* lA1 = &As[(wave * 32 + 16) * 32];
    unsigned short* lB0 = &Bs[(wave * 32) * 32];
    unsigned short* lB1 = &Bs[(wave * 32 + 16) * 32];

    const int fr = lane & 15;
    const int fk = (lane >> 4) * 8;
    const int wr = wave >> 1, wc = wave & 1;

    floatx4 acc[4][4];
#pragma unroll
    for (int i = 0; i < 4; i++)
#pragma unroll
        for (int j = 0; j < 4; j++) acc[i][j] = (floatx4){0.f, 0.f, 0.f, 0.f};

    for (int k0 = 0; k0 < K_; k0 += 32) {
        __syncthreads();
        async16(ag0 + k0, lA0);
        async16(ag1 + k0, lA1);
        async16(bg0 + k0, lB0);
        async16(bg1 + k0, lB1);
        __syncthreads();

        bf16x8 af[4], bfr[4];
#pragma unroll
        for (int i = 0; i < 4; i++)
            af[i] = *(const bf16x8*)&As[(wr * 64 + i * 16 + fr) * 32 + fk];
#pragma unroll
        for (int j = 0; j < 4; j++)
            bfr[j] = *(const bf16x8*)&Bs[(wc * 64 + j * 16 + fr) * 32 + fk];
#pragma unroll
        for (int i = 0; i < 4; i++)
#pragma unroll
            for (int j = 0; j < 4; j++)
                acc[i][j] = __builtin_amdgcn_mfma_f32_16x16x32_bf16(
                    af[i], bfr[j], acc[i][j], 0, 0, 0);
    }

    const int rbase = (lane >> 4) * 4;
    const int h = (n0 + wc * 64) >> 6;
    if (p == 2) {    // V transposed: [B,H,HS,T]
#pragma unroll
        for (int j = 0; j < 4; j++) {
            const int col = n0 + wc * 64 + j * 16 + fr;
            const float bz = bias[col];
            const int d = col & 63;
#pragma unroll
            for (int i = 0; i < 4; i++) {
                const int row0 = m0 + wr * 64 + i * 16 + rbase;
                const int bb = row0 >> 11, tt = row0 & 2047;
                ushort4 st;
                st.x = f2bf(acc[i][j][0] + bz);
                st.y = f2bf(acc[i][j][1] + bz);
                st.z = f2bf(acc[i][j][2] + bz);
                st.w = f2bf(acc[i][j][3] + bz);
                *(ushort4*)&vb[((size_t)(bb * H_ + h) * HS_ + d) * T_ + tt] = st;
            }
        }
    } else {
        unsigned short* out = (p == 0) ? qb : kb;
        const float qsc = (p == 0) ? 0.18033688011111772f : 1.0f;  // 0.125*log2(e)
        const float bz0 = bias[n0 + wc * 64 + fr];
        const float bz1 = bias[n0 + wc * 64 + 16 + fr];
        const float bz2 = bias[n0 + wc * 64 + 32 + fr];
        const float bz3 = bias[n0 + wc * 64 + 48 + fr];
        const float nl = -0.41524101186279297f;   // -log2(10000)/32
        const float if0 = exp2f((float)fr * nl);
        const float if1 = exp2f((float)(fr + 16) * nl);
#pragma unroll
        for (int i = 0; i < 4; i++) {
#pragma unroll
            for (int pr = 0; pr < 4; pr++) {
                const int row = m0 + wr * 64 + i * 16 + rbase + pr;
                const int bb = row >> 11, tt = row & 2047;
                float s0, c0, s1, c1;
                __sincosf((float)tt * if0, &s0, &c0);
                __sincosf((float)tt * if1, &s1, &c1);
                const float v0 = acc[i][0][pr] + bz0;
                const float v1 = acc[i][1][pr] + bz1;
                const float v2 = acc[i][2][pr] + bz2;
                const float v3 = acc[i][3][pr] + bz3;
                unsigned short* ob = out + ((size_t)(bb * H_ + h) * T_ + tt) * HS_ + fr;
                ob[0]  = f2bf((v0 * c0 - v2 * s0) * qsc);
                ob[16] = f2bf((v1 * c1 - v3 * s1) * qsc);
                ob[32] = f2bf((v2 * c0 + v0 * s0) * qsc);
                ob[48] = f2bf((v3 * c1 + v1 * s1) * qsc);
            }
        }
    }
}

// ---------------------------------------------------------------------------
// Kernel 3: MFMA flash attention, split-K flash-decoding.
// Slot s (=47-by, LPT): s<16 -> whole q-tile qt=s (<=16 key-tiles), write y.
// s>=16 -> qt = 16+((s-16)>>1), half = (s-16)&1: half key range, write
// unnormalized bf16 O' + fp32 m,l partials. grid (32, 48), block 256.
// ---------------------------------------------------------------------------
__global__ __launch_bounds__(256) void attn_kernel(
    const unsigned short* __restrict__ qb, const unsigned short* __restrict__ kb,
    const unsigned short* __restrict__ vt, unsigned short* __restrict__ yb,
    unsigned short* __restrict__ Opart, float* __restrict__ Mpart)
{
    __shared__ unsigned short Ks[2][64 * 64];
    __shared__ unsigned short Vs[2][64 * 64];
    __shared__ unsigned short Ps[4][16 * 64];

    const int bh = blockIdx.x;
    const int b = bh >> 4, h = bh & 15;
    const int s = 47 - (int)blockIdx.y;          // LPT: biggest first
    int qt, ktlo, kthi, half;
    bool split;
    if (s < 16) { qt = s; ktlo = 0; kthi = qt; half = 0; split = false; }
    else {
        const int idx = s - 16;
        qt = 16 + (idx >> 1); half = idx & 1;
        const int nf = (qt + 2) >> 1;            // ceil((qt+1)/2)
        ktlo = half ? nf : 0;
        kthi = half ? qt : nf - 1;
        split = true;
    }
    const int r0 = qt * 64;
    const int tid  = threadIdx.x;
    const int lane = tid & 63;
    const int wave = tid >> 6;
    const int l4   = lane & 15;
    const int quad = lane >> 4;

    const int qrow_g = r0 + wave * 16 + l4;

    bf16x8 qf[2];
    {
        const unsigned short* qp = qb + ((size_t)bh * T_ + qrow_g) * HS_ + quad * 8;
        qf[0] = *(const bf16x8*)(qp);
        qf[1] = *(const bf16x8*)(qp + 32);
    }

    floatx4 o[4];
#pragma unroll
    for (int g = 0; g < 4; g++) o[g] = (floatx4){0.f, 0.f, 0.f, 0.f};
    float m = -1e30f, l = 0.f;

    const int srow = tid >> 2;
    const int sc16 = (tid & 3) * 16;
    const int ssw  = (srow & 7) * 8;
    const int psw  = (l4 & 7) * 8;

    const unsigned short* kp = kb + ((size_t)bh * T_ + srow) * HS_ + sc16;
    const unsigned short* vp = vt + ((size_t)(bh * 64 + srow)) * T_ + sc16;

    // stage first tile into buffer 0
    uint4 rk0 = *(const uint4*)(kp + (size_t)ktlo * 64 * HS_);
    uint4 rk1 = *(const uint4*)(kp + (size_t)ktlo * 64 * HS_ + 8);
    uint4 rv0 = *(const uint4*)(vp + ktlo * 64);
    uint4 rv1 = *(const uint4*)(vp + ktlo * 64 + 8);
    *(uint4*)&Ks[0][srow * 64 + ( sc16      ^ ssw)] = rk0;
    *(uint4*)&Ks[0][srow * 64 + ((sc16 + 8) ^ ssw)] = rk1;
    *(uint4*)&Vs[0][srow * 64 + ( sc16      ^ ssw)] = rv0;
    *(uint4*)&Vs[0][srow * 64 + ((sc16 + 8) ^ ssw)] = rv1;

    for (int kt = ktlo; kt <= kthi; kt++) {
        const int cur = (kt - ktlo) & 1;
        if (kt < kthi) {   // register prefetch of next tile
            const unsigned short* kpn = kp + (size_t)(kt + 1) * (64 * HS_);
            const unsigned short* vpn = vp + (kt + 1) * 64;
            rk0 = *(const uint4*)kpn;
            rk1 = *(const uint4*)(kpn + 8);
            rv0 = *(const uint4*)vpn;
            rv1 = *(const uint4*)(vpn + 8);
        }
        __syncthreads();

        floatx4 sf[4];
#pragma unroll
        for (int mg = 0; mg < 4; mg++) {
            const int key = mg * 16 + l4;
            const int ksw = (key & 7) * 8;
            const bf16x8 a0 = *(const bf16x8*)&Ks[cur][key * 64 + ( (quad * 8)       ^ ksw)];
            const bf16x8 a1 = *(const bf16x8*)&Ks[cur][key * 64 + (((quad * 8) + 32) ^ ksw)];
            floatx4 z = (floatx4){0.f, 0.f, 0.f, 0.f};
            z = __builtin_amdgcn_mfma_f32_16x16x32_bf16(a0, qf[0], z, 0, 0, 0);
            z = __builtin_amdgcn_mfma_f32_16x16x32_bf16(a1, qf[1], z, 0, 0, 0);
            sf[mg] = z;
        }

        if (kt == qt) {   // causal mask on diagonal tile
#pragma unroll
            for (int mg = 0; mg < 4; mg++)
#pragma unroll
                for (int r = 0; r < 4; r++)
                    if (kt * 64 + 16 * mg + quad * 4 + r > qrow_g)
                        sf[mg][r] = -1e30f;
        }

        float tm = sf[0][0];
#pragma unroll
        for (int mg = 0; mg < 4; mg++)
#pragma unroll
            for (int r = 0; r < 4; r++) tm = fmaxf(tm, sf[mg][r]);
        tm = fmaxf(tm, __shfl_xor(tm, 16));
        tm = fmaxf(tm, __shfl_xor(tm, 32));
        const float mnew  = fmaxf(m, tm);
        const float alpha = __builtin_amdgcn_exp2f(m - mnew);

        float p[4][4];
        float ps = 0.f;
#pragma unroll
        for (int mg = 0; mg < 4; mg++)
#pragma unroll
            for (int r = 0; r < 4; r++) {
                p[mg][r] = __builtin_amdgcn_exp2f(sf[mg][r] - mnew);
                ps += p[mg][r];
            }
        ps += __shfl_xor(ps, 16);
        ps += __shfl_xor(ps, 32);
        l = l * alpha + ps;
        m = mnew;
#pragma unroll
        for (int g = 0; g < 4; g++) o[g] = o[g] * alpha;

#pragma unroll
        for (int mg = 0; mg < 4; mg++) {
            const int kb4 = 16 * mg + quad * 4;
            const int off = ((kb4 & ~7) ^ psw) | (kb4 & 7);
            uint2 w;
            w.x = pack2t(p[mg][0], p[mg][1]);    // v_perm truncating pack
            w.y = pack2t(p[mg][2], p[mg][3]);
            *(uint2*)&Ps[wave][l4 * 64 + off] = w;
        }

        const bf16x8 pf0 = *(const bf16x8*)&Ps[wave][l4 * 64 + ( (quad * 8)       ^ psw)];
        const bf16x8 pf1 = *(const bf16x8*)&Ps[wave][l4 * 64 + (((quad * 8) + 32) ^ psw)];
#pragma unroll
        for (int g = 0; g < 4; g++) {
            const int vd  = g * 16 + l4;
            const int vsw = (vd & 7) * 8;
            const bf16x8 va0 = *(const bf16x8*)&Vs[cur][vd * 64 + ( (quad * 8)       ^ vsw)];
            const bf16x8 va1 = *(const bf16x8*)&Vs[cur][vd * 64 + (((quad * 8) + 32) ^ vsw)];
            o[g] = __builtin_amdgcn_mfma_f32_16x16x32_bf16(va0, pf0, o[g], 0, 0, 0);
            o[g] = __builtin_amdgcn_mfma_f32_16x16x32_bf16(va1, pf1, o[g], 0, 0, 0);
        }

        if (kt < kthi) {   // stage prefetched tile into other buffer
            const int nxt = cur ^ 1;
            *(uint4*)&Ks[nxt][srow * 64 + ( sc16      ^ ssw)] = rk0;
            *(uint4*)&Ks[nxt][srow * 64 + ((sc16 + 8) ^ ssw)] = rk1;
            *(uint4*)&Vs[nxt][srow * 64 + ( sc16      ^ ssw)] = rv0;
            *(uint4*)&Vs[nxt][srow * 64 + ((sc16 + 8) ^ ssw)] = rv1;
        }
    }

    if (!split) {
        const float invl = 1.f / l;
        unsigned short* yrow = yb + ((size_t)(b * T_ + qrow_g) * H_ + h) * HS_;
#pragma unroll
        for (int g = 0; g < 4; g++) {
            ushort4 st;
            st.x = f2bf(o[g][0] * invl);
            st.y = f2bf(o[g][1] * invl);
            st.z = f2bf(o[g][2] * invl);
            st.w = f2bf(o[g][3] * invl);
            *(ushort4*)&yrow[16 * g + quad * 4] = st;
        }
    } else {
        const int u  = (bh * 16 + (qt - 16)) * 2 + half;
        const int rl = wave * 16 + l4;              // row-local 0..63
        unsigned short* Op = Opart + (size_t)u * 4096 + rl * 64;
#pragma unroll
        for (int g = 0; g < 4; g++) {
            ushort4 st;
            st.x = f2bf(o[g][0]);
            st.y = f2bf(o[g][1]);
            st.z = f2bf(o[g][2]);
            st.w = f2bf(o[g][3]);
            *(ushort4*)&Op[16 * g + quad * 4] = st;
        }
        if (quad == 0) {
            float* ml = Mpart + (size_t)u * 128;
            ml[rl]      = m;
            ml[64 + rl] = l;
        }
    }
}

// ---------------------------------------------------------------------------
// Kernel 3b: merge split-K partials. grid 512 (bh*16 + qt-16), block 256.
// ---------------------------------------------------------------------------
__global__ __launch_bounds__(256) void attn_combine(
    const unsigned short* __restrict__ Opart, const float* __restrict__ Mpart,
    unsigned short* __restrict__ yb)
{
    const int u  = blockIdx.x;
    const int bh = u >> 4, qt = 16 + (u & 15);
    const int b = bh >> 4, h = bh & 15;
    const int t = threadIdx.x;
    const int r = t >> 2, c = (t & 3) * 16;

    const float* ml1 = Mpart + (size_t)(u * 2) * 128;
    const float* ml2 = ml1 + 128;
    const float m1 = ml1[r], l1 = ml1[64 + r];
    const float m2 = ml2[r], l2 = ml2[64 + r];
    const float M  = fmaxf(m1, m2);
    const float w1 = __builtin_amdgcn_exp2f(m1 - M);
    const float w2 = __builtin_amdgcn_exp2f(m2 - M);
    const float inv = 1.f / (l1 * w1 + l2 * w2);
    const float a1 = w1 * inv, a2 = w2 * inv;

    const unsigned short* O1 = Opart + (size_t)(u * 2)     * 4096 + r * 64 + c;
    const unsigned short* O2 = Opart + (size_t)(u * 2 + 1) * 4096 + r * 64 + c;
    unsigned short* yrow = yb + ((size_t)(b * T_ + qt * 64 + r) * H_ + h) * HS_ + c;

#pragma unroll
    for (int j = 0; j < 2; j++) {
        const uint4 u1 = *(const uint4*)(O1 + 8 * j);
        const uint4 u2 = *(const uint4*)(O2 + 8 * j);
        const unsigned int a[4] = {u1.x, u1.y, u1.z, u1.w};
        const unsigned int d[4] = {u2.x, u2.y, u2.z, u2.w};
        unsigned int ov[4];
#pragma unroll
        for (int q = 0; q < 4; q++) {
            const float y0 = bf2f((unsigned short)(a[q] & 0xffff)) * a1
                           + bf2f((unsigned short)(d[q] & 0xffff)) * a2;
            const float y1 = bf2f((unsigned short)(a[q] >> 16)) * a1
                           + bf2f((unsigned short)(d[q] >> 16)) * a2;
            ov[q] = pack2(y0, y1);
        }
        *(uint4*)(yrow + 8 * j) = make_uint4(ov[0], ov[1], ov[2], ov[3]);
    }
}

// ---------------------------------------------------------------------------
// Kernel 4: output projection (unchanged). grid (8, 32), block 256.
// ---------------------------------------------------------------------------
__global__ __launch_bounds__(256) void out_gemm(
    const unsigned short* __restrict__ A, const unsigned short* __restrict__ wcT,
    const float* __restrict__ bias, float* __restrict__ out)
{
    __shared__ unsigned short As[128 * 32];
    __shared__ unsigned short Bs[128 * 32];

    const int tid  = threadIdx.x;
    const int lane = tid & 63;
    const int wave = tid >> 6;
    const int n0 = blockIdx.x * 128;
    const int m0 = blockIdx.y * 128;

    const int lrow = lane >> 2, lch = (lane & 3) * 8;
    const unsigned short* ag0 = A + (size_t)(m0 + wave * 32 + lrow) * K_ + lch;
    const unsigned short* ag1 = ag0 + (size_t)16 * K_;
    const unsigned short* bg0 = wcT + (size_t)(n0 + wave * 32 + lrow) * K_ + lch;
    const unsigned short* bg1 = bg0 + (size_t)16 * K_;
    unsigned short* lA0 = &As[(wave * 32) * 32];
    unsigned short* lA1 = &As[(wave * 32 + 16) * 32];
    unsigned short* lB0 = &Bs[(wave * 32) * 32];
    unsigned short* lB1 = &Bs[(wave * 32 + 16) * 32];

    const int fr = lane & 15;
    const int fk = (lane >> 4) * 8;
    const int wr = wave >> 1, wc = wave & 1;

    floatx4 acc[4][4];
#pragma unroll
    for (int i = 0; i < 4; i++)
#pragma unroll
        for (int j = 0; j < 4; j++) acc[i][j] = (floatx4){0.f, 0.f, 0.f, 0.f};

    for (int k0 = 0; k0 < K_; k0 += 32) {
        __syncthreads();
        async16(ag0 + k0, lA0);
        async16(ag1 + k0, lA1);
        async16(bg0 + k0, lB0);
        async16(bg1 + k0, lB1);
        __syncthreads();

        bf16x8 af[4], bfr[4];
#pragma unroll
        for (int i = 0; i < 4; i++)
            af[i] = *(const bf16x8*)&As[(wr * 64 + i * 16 + fr) * 32 + fk];
#pragma unroll
        for (int j = 0; j < 4; j++)
            bfr[j] = *(const bf16x8*)&Bs[(wc * 64 + j * 16 + fr) * 32 + fk];
#pragma unroll
        for (int i = 0; i < 4; i++)
#pragma unroll
            for (int j = 0; j < 4; j++)
                acc[i][j] = __builtin_amdgcn_mfma_f32_16x16x32_bf16(
                    af[i], bfr[j], acc[i][j], 0, 0, 0);
    }

    const int rbase = (lane >> 4) * 4;
#pragma unroll
    for (int j = 0; j < 4; j++) {
        const int col = n0 + wc * 64 + j * 16 + fr;
        const float bz = bias[col];
#pragma unroll
        for (int i = 0; i < 4; i++) {
#pragma unroll
            for (int pr = 0; pr < 4; pr++) {
                const int row = m0 + wr * 64 + i * 16 + rbase + pr;
                out[(size_t)row * N_ + col] = acc[i][j][pr] + bz;
            }
        }
    }
}

// ---------------------------------------------------------------------------
extern "C" void kernel_launch(void* const* d_in, const int* in_sizes, int n_in,
                              void* d_out, int out_size, void* d_ws, size_t ws_size,
                              hipStream_t stream) {
    const float* x  = (const float*)d_in[0];
    const float* wq = (const float*)d_in[1];
    const float* bq = (const float*)d_in[2];
    const float* wk = (const float*)d_in[3];
    const float* bk = (const float*)d_in[4];
    const float* wv = (const float*)d_in[5];
    const float* bv = (const float*)d_in[6];
    const float* wc = (const float*)d_in[7];
    const float* bc = (const float*)d_in[8];
    float* out = (float*)d_out;

    // ws (ushort units): qb 0, kb 4M, vb 8M, yb 12M, xb 16M, wT 20M..24M (48 MB)
    // After qkv_gemm, xb region is reused for split-K O' partials and the
    // wq-transpose region for m,l partials.
    unsigned short* ws  = (unsigned short*)d_ws;
    unsigned short* qb  = ws;                        // [B,H,T,HS] rope+scale
    unsigned short* kb  = ws + (size_t)4194304;      // [B,H,T,HS] rope
    unsigned short* vb  = ws + (size_t)8388608;      // [B,H,HS,T] (V^T)
    unsigned short* yb  = ws + (size_t)12582912;     // [B,T,C]
    unsigned short* xb  = ws + (size_t)16777216;     // x bf16 (dead after qkv)
    unsigned short* wT  = ws + (size_t)20971520;     // 4x bf16 [n][k]
    unsigned short* wcT = wT + ((size_t)3 << 20);
    unsigned short* Opart = xb;                      // 1024 x 4096 ushorts = 8 MB
    float*          Mpart = (float*)wT;              // 1024 x 128 floats = 512 KB

    convert_x<<<4096, 256, 0, stream>>>(x, xb);
    transpose_w<<<dim3(16, 16, 4), 256, 0, stream>>>(wq, wk, wv, wc, wT);
    qkv_gemm<<<dim3(24, 32), 256, 0, stream>>>(xb, wT, bq, bk, bv, qb, kb, vb);
    attn_kernel<<<dim3(32, 48), 256, 0, stream>>>(qb, kb, vb, yb, Opart, Mpart);
    attn_combine<<<512, 256, 0, stream>>>(Opart, Mpart, yb);
    out_gemm<<<dim3(8, 32), 256, 0, stream>>>(yb, wcT, bc, out);
}

// Round 9
// 195.923 us; speedup vs baseline: 13.0397x; 1.0776x over previous
//
#include <hip/hip_runtime.h>

#define B_  2
#define T_  2048
#define C_  1024
#define H_  16
#define HS_ 64
#define M_  4096
#define N_  1024
#define K_  1024

typedef float floatx4 __attribute__((ext_vector_type(4)));
typedef short bf16x8  __attribute__((ext_vector_type(8)));

__device__ __forceinline__ float bf2f(unsigned short u) {
    return __uint_as_float(((unsigned int)u) << 16);
}
__device__ __forceinline__ unsigned short f2bf(float f) {
    unsigned int u = __float_as_uint(f);
    return (unsigned short)((u + 0x7fffu + ((u >> 16) & 1u)) >> 16);
}
__device__ __forceinline__ unsigned int pack2(float a, float b) {
    return (unsigned int)f2bf(a) | ((unsigned int)f2bf(b) << 16);
}
// truncating bf16 pair pack: one v_perm_b32
__device__ __forceinline__ unsigned int pack2t(float a, float b) {
    return __builtin_amdgcn_perm(__float_as_uint(b), __float_as_uint(a), 0x07060302u);
}
// async global->LDS, 16B per lane; lds dest = wave-uniform base + lane*16
__device__ __forceinline__ void async16(const unsigned short* g, unsigned short* l) {
    __builtin_amdgcn_global_load_lds(
        (const __attribute__((address_space(1))) unsigned int*)g,
        (__attribute__((address_space(3))) unsigned int*)l, 16, 0, 0);
}

// ---------------------------------------------------------------------------
// Prep (merged): blocks 0..4095 convert x fp32->bf16; blocks 4096..5119
// transpose+convert weights (z = (bid-4096)>>8 selects wq/wk/wv/wc).
// grid 5120, block 256.
// ---------------------------------------------------------------------------
__global__ __launch_bounds__(256) void prep_kernel(
    const float* __restrict__ x,
    const float* __restrict__ w0, const float* __restrict__ w1,
    const float* __restrict__ w2, const float* __restrict__ w3,
    unsigned short* __restrict__ xb, unsigned short* __restrict__ wTall)
{
    __shared__ float tile[64][65];
    const int bid = blockIdx.x;
    const int t = threadIdx.x;
    if (bid < 4096) {
        const size_t i = ((size_t)bid * 256 + t) * 4;
        const float4 v = *(const float4*)(x + i);
        ushort4 st;
        st.x = f2bf(v.x); st.y = f2bf(v.y); st.z = f2bf(v.z); st.w = f2bf(v.w);
        *(ushort4*)(xb + i) = st;
        return;
    }
    const int zb = bid - 4096;
    const int z = zb >> 8, rem = zb & 255;
    const float* w = (z == 0) ? w0 : (z == 1) ? w1 : (z == 2) ? w2 : w3;
    unsigned short* wT = wTall + ((size_t)z << 20);
    const int n0 = (rem & 15) * 64, k0 = (rem >> 4) * 64;

    const int r = t >> 2, cq = (t & 3) * 16;
    const float4* src = (const float4*)(w + (size_t)(k0 + r) * N_ + n0 + cq);
    const float4 v0 = src[0], v1 = src[1], v2 = src[2], v3 = src[3];
    tile[r][cq+0]=v0.x; tile[r][cq+1]=v0.y; tile[r][cq+2]=v0.z; tile[r][cq+3]=v0.w;
    tile[r][cq+4]=v1.x; tile[r][cq+5]=v1.y; tile[r][cq+6]=v1.z; tile[r][cq+7]=v1.w;
    tile[r][cq+8]=v2.x; tile[r][cq+9]=v2.y; tile[r][cq+10]=v2.z; tile[r][cq+11]=v2.w;
    tile[r][cq+12]=v3.x; tile[r][cq+13]=v3.y; tile[r][cq+14]=v3.z; tile[r][cq+15]=v3.w;
    __syncthreads();

    const int rn = t >> 2, ck = (t & 3) * 16;
    unsigned int o[8];
#pragma unroll
    for (int ii = 0; ii < 8; ii++)
        o[ii] = pack2(tile[ck + 2*ii][rn], tile[ck + 2*ii + 1][rn]);
    unsigned short* dst = wT + (size_t)(n0 + rn) * K_ + k0 + ck;
    *(uint4*)dst       = make_uint4(o[0], o[1], o[2], o[3]);
    *(uint4*)(dst + 8) = make_uint4(o[4], o[5], o[6], o[7]);
}

// ---------------------------------------------------------------------------
// Kernel 1: fused QKV GEMM + RoPE epilogue. BK=64 as two BK=32 sub-tiles
// (same LDS layout/bank pattern as BK=32, half the barriers).
// grid (24, 32), block 256.
// ---------------------------------------------------------------------------
__global__ __launch_bounds__(256) void qkv_gemm(
    const unsigned short* __restrict__ xb, const unsigned short* __restrict__ wT,
    const float* __restrict__ bq, const float* __restrict__ bk,
    const float* __restrict__ bv,
    unsigned short* __restrict__ qb, unsigned short* __restrict__ kb,
    unsigned short* __restrict__ vb)
{
    __shared__ unsigned short As[2 * 128 * 32];   // [kh][m][k]
    __shared__ unsigned short Bs[2 * 128 * 32];   // [kh][n][k]

    const int tid  = threadIdx.x;
    const int lane = tid & 63;
    const int wave = tid >> 6;
    const int p  = blockIdx.x >> 3;
    const int n0 = (blockIdx.x & 7) * 128;
    const int m0 = blockIdx.y * 128;
    const float* bias = (p == 0) ? bq : (p == 1) ? bk : bv;

    // staging: lane l -> row l>>2, 8-elem chunk l&3 (matches lane*16B dest)
    const int lrow = lane >> 2, lch = (lane & 3) * 8;
    const unsigned short* ag0 = xb + (size_t)(m0 + wave * 32 + lrow) * K_ + lch;
    const unsigned short* ag1 = ag0 + (size_t)16 * K_;
    const unsigned short* wb  = wT + ((size_t)p << 20);
    const unsigned short* bg0 = wb + (size_t)(n0 + wave * 32 + lrow) * K_ + lch;
    const unsigned short* bg1 = bg0 + (size_t)16 * K_;
    unsigned short* lA00 = &As[(wave * 32) * 32];           // kh=0, c=0
    unsigned short* lA01 = &As[(wave * 32 + 16) * 32];      // kh=0, c=1
    unsigned short* lA10 = lA00 + 4096;                     // kh=1
    unsigned short* lA11 = lA01 + 4096;
    unsigned short* lB00 = &Bs[(wave * 32) * 32];
    unsigned short* lB01 = &Bs[(wave * 32 + 16) * 32];
    unsigned short* lB10 = lB00 + 4096;
    unsigned short* lB11 = lB01 + 4096;

    const int fr = lane & 15;
    const int fk = (lane >> 4) * 8;
    const int wr = wave >> 1, wc = wave & 1;

    floatx4 acc[4][4];
#pragma unroll
    for (int i = 0; i < 4; i++)
#pragma unroll
        for (int j = 0; j < 4; j++) acc[i][j] = (floatx4){0.f, 0.f, 0.f, 0.f};

    for (int k0 = 0; k0 < K_; k0 += 64) {
        __syncthreads();
        async16(ag0 + k0,      lA00);
        async16(ag1 + k0,      lA01);
        async16(ag0 + k0 + 32, lA10);
        async16(ag1 + k0 + 32, lA11);
        async16(bg0 + k0,      lB00);
        async16(bg1 + k0,      lB01);
        async16(bg0 + k0 + 32, lB10);
        async16(bg1 + k0 + 32, lB11);
        __syncthreads();

#pragma unroll
        for (int kh = 0; kh < 2; kh++) {
            const unsigned short* Ah = &As[kh * 4096];
            const unsigned short* Bh = &Bs[kh * 4096];
            bf16x8 af[4], bfr[4];
#pragma unroll
            for (int i = 0; i < 4; i++)
                af[i] = *(const bf16x8*)&Ah[(wr * 64 + i * 16 + fr) * 32 + fk];
#pragma unroll
            for (int j = 0; j < 4; j++)
                bfr[j] = *(const bf16x8*)&Bh[(wc * 64 + j * 16 + fr) * 32 + fk];
#pragma unroll
            for (int i = 0; i < 4; i++)
#pragma unroll
                for (int j = 0; j < 4; j++)
                    acc[i][j] = __builtin_amdgcn_mfma_f32_16x16x32_bf16(
                        af[i], bfr[j], acc[i][j], 0, 0, 0);
        }
    }

    const int rbase = (lane >> 4) * 4;
    const int h = (n0 + wc * 64) >> 6;
    if (p == 2) {    // V transposed: [B,H,HS,T]
#pragma unroll
        for (int j = 0; j < 4; j++) {
            const int col = n0 + wc * 64 + j * 16 + fr;
            const float bz = bias[col];
            const int d = col & 63;
#pragma unroll
            for (int i = 0; i < 4; i++) {
                const int row0 = m0 + wr * 64 + i * 16 + rbase;
                const int bb = row0 >> 11, tt = row0 & 2047;
                ushort4 st;
                st.x = f2bf(acc[i][j][0] + bz);
                st.y = f2bf(acc[i][j][1] + bz);
                st.z = f2bf(acc[i][j][2] + bz);
                st.w = f2bf(acc[i][j][3] + bz);
                *(ushort4*)&vb[((size_t)(bb * H_ + h) * HS_ + d) * T_ + tt] = st;
            }
        }
    } else {
        unsigned short* out = (p == 0) ? qb : kb;
        const float qsc = (p == 0) ? 0.18033688011111772f : 1.0f;  // 0.125*log2(e)
        const float bz0 = bias[n0 + wc * 64 + fr];
        const float bz1 = bias[n0 + wc * 64 + 16 + fr];
        const float bz2 = bias[n0 + wc * 64 + 32 + fr];
        const float bz3 = bias[n0 + wc * 64 + 48 + fr];
        const float nl = -0.41524101186279297f;   // -log2(10000)/32
        const float if0 = exp2f((float)fr * nl);
        const float if1 = exp2f((float)(fr + 16) * nl);
#pragma unroll
        for (int i = 0; i < 4; i++) {
#pragma unroll
            for (int pr = 0; pr < 4; pr++) {
                const int row = m0 + wr * 64 + i * 16 + rbase + pr;
                const int bb = row >> 11, tt = row & 2047;
                float s0, c0, s1, c1;
                __sincosf((float)tt * if0, &s0, &c0);
                __sincosf((float)tt * if1, &s1, &c1);
                const float v0 = acc[i][0][pr] + bz0;
                const float v1 = acc[i][1][pr] + bz1;
                const float v2 = acc[i][2][pr] + bz2;
                const float v3 = acc[i][3][pr] + bz3;
                unsigned short* ob = out + ((size_t)(bb * H_ + h) * T_ + tt) * HS_ + fr;
                ob[0]  = f2bf((v0 * c0 - v2 * s0) * qsc);
                ob[16] = f2bf((v1 * c1 - v3 * s1) * qsc);
                ob[32] = f2bf((v2 * c0 + v0 * s0) * qsc);
                ob[48] = f2bf((v3 * c1 + v1 * s1) * qsc);
            }
        }
    }
}

// ---------------------------------------------------------------------------
// Kernel 3: MFMA flash attention, split-K flash-decoding (unchanged).
// grid (32, 48), block 256.
// ---------------------------------------------------------------------------
__global__ __launch_bounds__(256) void attn_kernel(
    const unsigned short* __restrict__ qb, const unsigned short* __restrict__ kb,
    const unsigned short* __restrict__ vt, unsigned short* __restrict__ yb,
    unsigned short* __restrict__ Opart, float* __restrict__ Mpart)
{
    __shared__ unsigned short Ks[2][64 * 64];
    __shared__ unsigned short Vs[2][64 * 64];
    __shared__ unsigned short Ps[4][16 * 64];

    const int bh = blockIdx.x;
    const int b = bh >> 4, h = bh & 15;
    const int s = 47 - (int)blockIdx.y;          // LPT: biggest first
    int qt, ktlo, kthi, half;
    bool split;
    if (s < 16) { qt = s; ktlo = 0; kthi = qt; half = 0; split = false; }
    else {
        const int idx = s - 16;
        qt = 16 + (idx >> 1); half = idx & 1;
        const int nf = (qt + 2) >> 1;
        ktlo = half ? nf : 0;
        kthi = half ? qt : nf - 1;
        split = true;
    }
    const int r0 = qt * 64;
    const int tid  = threadIdx.x;
    const int lane = tid & 63;
    const int wave = tid >> 6;
    const int l4   = lane & 15;
    const int quad = lane >> 4;

    const int qrow_g = r0 + wave * 16 + l4;

    bf16x8 qf[2];
    {
        const unsigned short* qp = qb + ((size_t)bh * T_ + qrow_g) * HS_ + quad * 8;
        qf[0] = *(const bf16x8*)(qp);
        qf[1] = *(const bf16x8*)(qp + 32);
    }

    floatx4 o[4];
#pragma unroll
    for (int g = 0; g < 4; g++) o[g] = (floatx4){0.f, 0.f, 0.f, 0.f};
    float m = -1e30f, l = 0.f;

    const int srow = tid >> 2;
    const int sc16 = (tid & 3) * 16;
    const int ssw  = (srow & 7) * 8;
    const int psw  = (l4 & 7) * 8;

    const unsigned short* kp = kb + ((size_t)bh * T_ + srow) * HS_ + sc16;
    const unsigned short* vp = vt + ((size_t)(bh * 64 + srow)) * T_ + sc16;

    uint4 rk0 = *(const uint4*)(kp + (size_t)ktlo * 64 * HS_);
    uint4 rk1 = *(const uint4*)(kp + (size_t)ktlo * 64 * HS_ + 8);
    uint4 rv0 = *(const uint4*)(vp + ktlo * 64);
    uint4 rv1 = *(const uint4*)(vp + ktlo * 64 + 8);
    *(uint4*)&Ks[0][srow * 64 + ( sc16      ^ ssw)] = rk0;
    *(uint4*)&Ks[0][srow * 64 + ((sc16 + 8) ^ ssw)] = rk1;
    *(uint4*)&Vs[0][srow * 64 + ( sc16      ^ ssw)] = rv0;
    *(uint4*)&Vs[0][srow * 64 + ((sc16 + 8) ^ ssw)] = rv1;

    for (int kt = ktlo; kt <= kthi; kt++) {
        const int cur = (kt - ktlo) & 1;
        if (kt < kthi) {
            const unsigned short* kpn = kp + (size_t)(kt + 1) * (64 * HS_);
            const unsigned short* vpn = vp + (kt + 1) * 64;
            rk0 = *(const uint4*)kpn;
            rk1 = *(const uint4*)(kpn + 8);
            rv0 = *(const uint4*)vpn;
            rv1 = *(const uint4*)(vpn + 8);
        }
        __syncthreads();

        floatx4 sf[4];
#pragma unroll
        for (int mg = 0; mg < 4; mg++) {
            const int key = mg * 16 + l4;
            const int ksw = (key & 7) * 8;
            const bf16x8 a0 = *(const bf16x8*)&Ks[cur][key * 64 + ( (quad * 8)       ^ ksw)];
            const bf16x8 a1 = *(const bf16x8*)&Ks[cur][key * 64 + (((quad * 8) + 32) ^ ksw)];
            floatx4 z = (floatx4){0.f, 0.f, 0.f, 0.f};
            z = __builtin_amdgcn_mfma_f32_16x16x32_bf16(a0, qf[0], z, 0, 0, 0);
            z = __builtin_amdgcn_mfma_f32_16x16x32_bf16(a1, qf[1], z, 0, 0, 0);
            sf[mg] = z;
        }

        if (kt == qt) {
#pragma unroll
            for (int mg = 0; mg < 4; mg++)
#pragma unroll
                for (int r = 0; r < 4; r++)
                    if (kt * 64 + 16 * mg + quad * 4 + r > qrow_g)
                        sf[mg][r] = -1e30f;
        }

        float tm = sf[0][0];
#pragma unroll
        for (int mg = 0; mg < 4; mg++)
#pragma unroll
            for (int r = 0; r < 4; r++) tm = fmaxf(tm, sf[mg][r]);
        tm = fmaxf(tm, __shfl_xor(tm, 16));
        tm = fmaxf(tm, __shfl_xor(tm, 32));
        const float mnew  = fmaxf(m, tm);
        const float alpha = __builtin_amdgcn_exp2f(m - mnew);

        float p[4][4];
        float ps = 0.f;
#pragma unroll
        for (int mg = 0; mg < 4; mg++)
#pragma unroll
            for (int r = 0; r < 4; r++) {
                p[mg][r] = __builtin_amdgcn_exp2f(sf[mg][r] - mnew);
                ps += p[mg][r];
            }
        ps += __shfl_xor(ps, 16);
        ps += __shfl_xor(ps, 32);
        l = l * alpha + ps;
        m = mnew;
#pragma unroll
        for (int g = 0; g < 4; g++) o[g] = o[g] * alpha;

#pragma unroll
        for (int mg = 0; mg < 4; mg++) {
            const int kb4 = 16 * mg + quad * 4;
            const int off = ((kb4 & ~7) ^ psw) | (kb4 & 7);
            uint2 w;
            w.x = pack2t(p[mg][0], p[mg][1]);
            w.y = pack2t(p[mg][2], p[mg][3]);
            *(uint2*)&Ps[wave][l4 * 64 + off] = w;
        }

        const bf16x8 pf0 = *(const bf16x8*)&Ps[wave][l4 * 64 + ( (quad * 8)       ^ psw)];
        const bf16x8 pf1 = *(const bf16x8*)&Ps[wave][l4 * 64 + (((quad * 8) + 32) ^ psw)];
#pragma unroll
        for (int g = 0; g < 4; g++) {
            const int vd  = g * 16 + l4;
            const int vsw = (vd & 7) * 8;
            const bf16x8 va0 = *(const bf16x8*)&Vs[cur][vd * 64 + ( (quad * 8)       ^ vsw)];
            const bf16x8 va1 = *(const bf16x8*)&Vs[cur][vd * 64 + (((quad * 8) + 32) ^ vsw)];
            o[g] = __builtin_amdgcn_mfma_f32_16x16x32_bf16(va0, pf0, o[g], 0, 0, 0);
            o[g] = __builtin_amdgcn_mfma_f32_16x16x32_bf16(va1, pf1, o[g], 0, 0, 0);
        }

        if (kt < kthi) {
            const int nxt = cur ^ 1;
            *(uint4*)&Ks[nxt][srow * 64 + ( sc16      ^ ssw)] = rk0;
            *(uint4*)&Ks[nxt][srow * 64 + ((sc16 + 8) ^ ssw)] = rk1;
            *(uint4*)&Vs[nxt][srow * 64 + ( sc16      ^ ssw)] = rv0;
            *(uint4*)&Vs[nxt][srow * 64 + ((sc16 + 8) ^ ssw)] = rv1;
        }
    }

    if (!split) {
        const float invl = 1.f / l;
        unsigned short* yrow = yb + ((size_t)(b * T_ + qrow_g) * H_ + h) * HS_;
#pragma unroll
        for (int g = 0; g < 4; g++) {
            ushort4 st;
            st.x = f2bf(o[g][0] * invl);
            st.y = f2bf(o[g][1] * invl);
            st.z = f2bf(o[g][2] * invl);
            st.w = f2bf(o[g][3] * invl);
            *(ushort4*)&yrow[16 * g + quad * 4] = st;
        }
    } else {
        const int u  = (bh * 16 + (qt - 16)) * 2 + half;
        const int rl = wave * 16 + l4;
        unsigned short* Op = Opart + (size_t)u * 4096 + rl * 64;
#pragma unroll
        for (int g = 0; g < 4; g++) {
            ushort4 st;
            st.x = f2bf(o[g][0]);
            st.y = f2bf(o[g][1]);
            st.z = f2bf(o[g][2]);
            st.w = f2bf(o[g][3]);
            *(ushort4*)&Op[16 * g + quad * 4] = st;
        }
        if (quad == 0) {
            float* ml = Mpart + (size_t)u * 128;
            ml[rl]      = m;
            ml[64 + rl] = l;
        }
    }
}

// ---------------------------------------------------------------------------
// Kernel 3b: merge split-K partials. grid 512, block 256.
// ---------------------------------------------------------------------------
__global__ __launch_bounds__(256) void attn_combine(
    const unsigned short* __restrict__ Opart, const float* __restrict__ Mpart,
    unsigned short* __restrict__ yb)
{
    const int u  = blockIdx.x;
    const int bh = u >> 4, qt = 16 + (u & 15);
    const int b = bh >> 4, h = bh & 15;
    const int t = threadIdx.x;
    const int r = t >> 2, c = (t & 3) * 16;

    const float* ml1 = Mpart + (size_t)(u * 2) * 128;
    const float* ml2 = ml1 + 128;
    const float m1 = ml1[r], l1 = ml1[64 + r];
    const float m2 = ml2[r], l2 = ml2[64 + r];
    const float M  = fmaxf(m1, m2);
    const float w1 = __builtin_amdgcn_exp2f(m1 - M);
    const float w2 = __builtin_amdgcn_exp2f(m2 - M);
    const float inv = 1.f / (l1 * w1 + l2 * w2);
    const float a1 = w1 * inv, a2 = w2 * inv;

    const unsigned short* O1 = Opart + (size_t)(u * 2)     * 4096 + r * 64 + c;
    const unsigned short* O2 = Opart + (size_t)(u * 2 + 1) * 4096 + r * 64 + c;
    unsigned short* yrow = yb + ((size_t)(b * T_ + qt * 64 + r) * H_ + h) * HS_ + c;

#pragma unroll
    for (int j = 0; j < 2; j++) {
        const uint4 u1 = *(const uint4*)(O1 + 8 * j);
        const uint4 u2 = *(const uint4*)(O2 + 8 * j);
        const unsigned int a[4] = {u1.x, u1.y, u1.z, u1.w};
        const unsigned int d[4] = {u2.x, u2.y, u2.z, u2.w};
        unsigned int ov[4];
#pragma unroll
        for (int q = 0; q < 4; q++) {
            const float y0 = bf2f((unsigned short)(a[q] & 0xffff)) * a1
                           + bf2f((unsigned short)(d[q] & 0xffff)) * a2;
            const float y1 = bf2f((unsigned short)(a[q] >> 16)) * a1
                           + bf2f((unsigned short)(d[q] >> 16)) * a2;
            ov[q] = pack2(y0, y1);
        }
        *(uint4*)(yrow + 8 * j) = make_uint4(ov[0], ov[1], ov[2], ov[3]);
    }
}

// ---------------------------------------------------------------------------
// Kernel 4: output projection. 64(M)x128(N) tiles, BK=64 (two sub-tiles).
// grid (8, 64) = 512 blocks, block 256. Waves 2x2 over (64,128).
// ---------------------------------------------------------------------------
__global__ __launch_bounds__(256) void out_gemm(
    const unsigned short* __restrict__ A, const unsigned short* __restrict__ wcT,
    const float* __restrict__ bias, float* __restrict__ out)
{
    __shared__ unsigned short As[2 * 64 * 32];    // [kh][m][k]
    __shared__ unsigned short Bs[2 * 128 * 32];   // [kh][n][k]

    const int tid  = threadIdx.x;
    const int lane = tid & 63;
    const int wave = tid >> 6;
    const int n0 = blockIdx.x * 128;
    const int m0 = blockIdx.y * 64;

    const int lrow = lane >> 2, lch = (lane & 3) * 8;
    const unsigned short* ag  = A   + (size_t)(m0 + wave * 16 + lrow) * K_ + lch;
    const unsigned short* bg0 = wcT + (size_t)(n0 + wave * 32 + lrow) * K_ + lch;
    const unsigned short* bg1 = bg0 + (size_t)16 * K_;
    unsigned short* lA0  = &As[(wave * 16) * 32];
    unsigned short* lA1  = lA0 + 2048;                 // kh=1
    unsigned short* lB00 = &Bs[(wave * 32) * 32];
    unsigned short* lB01 = &Bs[(wave * 32 + 16) * 32];
    unsigned short* lB10 = lB00 + 4096;
    unsigned short* lB11 = lB01 + 4096;

    const int fr = lane & 15;
    const int fk = (lane >> 4) * 8;
    const int wr2 = wave >> 1, wc2 = wave & 1;

    floatx4 acc[2][4];
#pragma unroll
    for (int i = 0; i < 2; i++)
#pragma unroll
        for (int j = 0; j < 4; j++) acc[i][j] = (floatx4){0.f, 0.f, 0.f, 0.f};

    for (int k0 = 0; k0 < K_; k0 += 64) {
        __syncthreads();
        async16(ag  + k0,      lA0);
        async16(ag  + k0 + 32, lA1);
        async16(bg0 + k0,      lB00);
        async16(bg1 + k0,      lB01);
        async16(bg0 + k0 + 32, lB10);
        async16(bg1 + k0 + 32, lB11);
        __syncthreads();

#pragma unroll
        for (int kh = 0; kh < 2; kh++) {
            const unsigned short* Ah = &As[kh * 2048];
            const unsigned short* Bh = &Bs[kh * 4096];
            bf16x8 af[2], bfr[4];
#pragma unroll
            for (int i = 0; i < 2; i++)
                af[i] = *(const bf16x8*)&Ah[(wr2 * 32 + i * 16 + fr) * 32 + fk];
#pragma unroll
            for (int j = 0; j < 4; j++)
                bfr[j] = *(const bf16x8*)&Bh[(wc2 * 64 + j * 16 + fr) * 32 + fk];
#pragma unroll
            for (int i = 0; i < 2; i++)
#pragma unroll
                for (int j = 0; j < 4; j++)
                    acc[i][j] = __builtin_amdgcn_mfma_f32_16x16x32_bf16(
                        af[i], bfr[j], acc[i][j], 0, 0, 0);
        }
    }

    const int rbase = (lane >> 4) * 4;
#pragma unroll
    for (int j = 0; j < 4; j++) {
        const int col = n0 + wc2 * 64 + j * 16 + fr;
        const float bz = bias[col];
#pragma unroll
        for (int i = 0; i < 2; i++) {
#pragma unroll
            for (int pr = 0; pr < 4; pr++) {
                const int row = m0 + wr2 * 32 + i * 16 + rbase + pr;
                out[(size_t)row * N_ + col] = acc[i][j][pr] + bz;
            }
        }
    }
}

// ---------------------------------------------------------------------------
extern "C" void kernel_launch(void* const* d_in, const int* in_sizes, int n_in,
                              void* d_out, int out_size, void* d_ws, size_t ws_size,
                              hipStream_t stream) {
    const float* x  = (const float*)d_in[0];
    const float* wq = (const float*)d_in[1];
    const float* bq = (const float*)d_in[2];
    const float* wk = (const float*)d_in[3];
    const float* bk = (const float*)d_in[4];
    const float* wv = (const float*)d_in[5];
    const float* bv = (const float*)d_in[6];
    const float* wc = (const float*)d_in[7];
    const float* bc = (const float*)d_in[8];
    float* out = (float*)d_out;

    // ws (ushort units): qb 0, kb 4M, vb 8M, yb 12M, xb 16M, wT 20M..24M (48 MB)
    unsigned short* ws  = (unsigned short*)d_ws;
    unsigned short* qb  = ws;                        // [B,H,T,HS] rope+scale
    unsigned short* kb  = ws + (size_t)4194304;      // [B,H,T,HS] rope
    unsigned short* vb  = ws + (size_t)8388608;      // [B,H,HS,T] (V^T)
    unsigned short* yb  = ws + (size_t)12582912;     // [B,T,C]
    unsigned short* xb  = ws + (size_t)16777216;     // x bf16 (dead after qkv)
    unsigned short* wT  = ws + (size_t)20971520;     // 4x bf16 [n][k]
    unsigned short* wcT = wT + ((size_t)3 << 20);
    unsigned short* Opart = xb;                      // split-K O' partials
    float*          Mpart = (float*)wT;              // split-K m,l partials

    prep_kernel<<<5120, 256, 0, stream>>>(x, wq, wk, wv, wc, xb, wT);
    qkv_gemm<<<dim3(24, 32), 256, 0, stream>>>(xb, wT, bq, bk, bv, qb, kb, vb);
    attn_kernel<<<dim3(32, 48), 256, 0, stream>>>(qb, kb, vb, yb, Opart, Mpart);
    attn_combine<<<512, 256, 0, stream>>>(Opart, Mpart, yb);
    out_gemm<<<dim3(8, 64), 256, 0, stream>>>(yb, wcT, bc, out);
}